// Round 9
// baseline (344.616 us; speedup 1.0000x reference)
//
#include <hip/hip_runtime.h>
#include <hip/hip_bf16.h>
#include <math.h>

#define N_NODES 50000
#define N_EDGES 800000
#define ET_EDGES (N_EDGES + N_NODES)   // with self-loops
#define NEG_SLOPE 0.2f
#define NBLK ((N_NODES + 255) / 256)   // 196 scan blocks
#define NBUCK ((N_NODES + 255) / 256)  // 196 dst buckets (256 nodes each)
#define CHUNK 4096                      // edges per binning block

typedef __hip_bfloat16 bf16;

__device__ inline float bfbits(unsigned short u) {
    return __uint_as_float(((unsigned)u) << 16);
}
__device__ inline float bflo(unsigned u) { return __uint_as_float(u << 16); }
__device__ inline float bfhi(unsigned u) { return __uint_as_float(u & 0xffff0000u); }

// ---------------- dtype detection ----------------
__global__ void detect_dtype(const unsigned short* __restrict__ w1raw,
                             unsigned* __restrict__ flag)
{
    int t = threadIdx.x;
    float v0 = bfbits(w1raw[2 * t]);
    float v1 = bfbits(w1raw[2 * t + 1]);
    bool bad = !(fabsf(v0) <= 64.f && fabsf(v1) <= 64.f);  // NaN -> bad
    unsigned long long b = __ballot(bad);
    if (t == 0) *flag = (b == 0ull) ? 1u : 0u;
}

// ---------------- param conversion (12 small tensors -> fp32) ----------------
struct CvtArgs {
    const void* src[12];
    float*      dst[12];
    int         n[12];
};

__global__ __launch_bounds__(256)
void convert_params(CvtArgs a, const unsigned* __restrict__ flag)
{
    bool isbf = (*flag != 0u);
    int which = blockIdx.y;
    int n = a.n[which];
    const void* s = a.src[which];
    float* d = a.dst[which];
    for (int i = blockIdx.x * 256 + threadIdx.x; i < n; i += gridDim.x * 256) {
        d[i] = isbf ? bfbits(((const unsigned short*)s)[i])
                    : ((const float*)s)[i];
    }
}

// ---------------- CSR build: degree histogram + rowptr scan ----------------
__global__ __launch_bounds__(256)
void edge_hist(const int* __restrict__ ei, int* __restrict__ deg)
{
    int e = blockIdx.x * 256 + threadIdx.x;
    if (e >= ET_EDGES) return;
    int d = (e < N_EDGES) ? ei[N_EDGES + e] : e - N_EDGES;
    atomicAdd(&deg[d], 1);
}

__global__ __launch_bounds__(256)
void scan1(const int* __restrict__ deg, int* __restrict__ bsum)
{
    __shared__ int s[256];
    int i = blockIdx.x * 256 + threadIdx.x;
    s[threadIdx.x] = (i < N_NODES) ? deg[i] : 0;
    __syncthreads();
    for (int off = 128; off > 0; off >>= 1) {
        if (threadIdx.x < off) s[threadIdx.x] += s[threadIdx.x + off];
        __syncthreads();
    }
    if (threadIdx.x == 0) bsum[blockIdx.x] = s[0];
}

__global__ __launch_bounds__(256)
void scan2(int* __restrict__ bsum)
{
    __shared__ int s[256];
    int t = threadIdx.x;
    int v = (t < NBLK) ? bsum[t] : 0;
    s[t] = v;
    __syncthreads();
    for (int off = 1; off < 256; off <<= 1) {
        int u = (t >= off) ? s[t - off] : 0;
        __syncthreads();
        s[t] += u;
        __syncthreads();
    }
    if (t < NBLK) bsum[t] = s[t] - v;   // exclusive
}

__global__ __launch_bounds__(256)
void scan3(const int* __restrict__ deg, const int* __restrict__ bsum,
           int* __restrict__ rowptr, int* __restrict__ cur256)
{
    __shared__ int s[256];
    int i = blockIdx.x * 256 + threadIdx.x;
    int v = (i < N_NODES) ? deg[i] : 0;
    s[threadIdx.x] = v;
    __syncthreads();
    for (int off = 1; off < 256; off <<= 1) {
        int t = (threadIdx.x >= off) ? s[threadIdx.x - off] : 0;
        __syncthreads();
        s[threadIdx.x] += t;
        __syncthreads();
    }
    if (i < N_NODES) {
        int excl = s[threadIdx.x] - v + bsum[blockIdx.x];
        rowptr[i] = excl;
        if (threadIdx.x == 0) cur256[blockIdx.x] = excl;  // bucket cursor base
    }
    if (i == 0) rowptr[N_NODES] = ET_EDGES;
}

// ---------------- Pass C: bin edges by dst bucket into scratch --------------
__global__ __launch_bounds__(256)
void binpass(const int* __restrict__ ei, int* __restrict__ cur256,
             unsigned* __restrict__ scratch)
{
    __shared__ int hist[NBUCK];
    __shared__ int lpre[NBUCK + 1];
    __shared__ int lcur[NBUCK];
    __shared__ int gbase[NBUCK];
    __shared__ int scan_a[256];
    __shared__ unsigned entry[CHUNK];

    const int tid = threadIdx.x;
    const int e0  = blockIdx.x * CHUNK;
    const int n   = min(CHUNK, ET_EDGES - e0);

    if (tid < NBUCK) hist[tid] = 0;
    __syncthreads();

    for (int k = tid; k < n; k += 256) {
        int e = e0 + k;
        int d = (e < N_EDGES) ? ei[N_EDGES + e] : e - N_EDGES;
        atomicAdd(&hist[d >> 8], 1);
    }
    __syncthreads();

    int v = (tid < NBUCK) ? hist[tid] : 0;
    scan_a[tid] = v;
    __syncthreads();
    for (int off = 1; off < 256; off <<= 1) {
        int t = (tid >= off) ? scan_a[tid - off] : 0;
        __syncthreads();
        scan_a[tid] += t;
        __syncthreads();
    }
    if (tid < NBUCK) lpre[tid] = scan_a[tid] - v;
    if (tid == NBUCK - 1) lpre[NBUCK] = scan_a[tid];
    if (tid < NBUCK) {
        gbase[tid] = v ? atomicAdd(&cur256[tid], v) : 0;
        lcur[tid] = 0;
    }
    __syncthreads();

    for (int k = tid; k < n; k += 256) {
        int e = e0 + k;
        int s, d;
        if (e < N_EDGES) { s = ei[e]; d = ei[N_EDGES + e]; }
        else             { s = d = e - N_EDGES; }
        int b = d >> 8;
        int p = atomicAdd(&lcur[b], 1);
        entry[lpre[b] + p] = ((unsigned)s << 8) | (unsigned)(d & 255);
    }
    __syncthreads();

    for (int i = tid; i < n; i += 256) {
        int lo = 0, hi = NBUCK;
        while (hi - lo > 1) {
            int mid = (lo + hi) >> 1;
            if (lpre[mid] <= i) lo = mid; else hi = mid;
        }
        scratch[gbase[lo] + (i - lpre[lo])] = entry[i];
    }
}

// ---------------- Pass D: fine scatter within each bucket -------------------
__global__ __launch_bounds__(256)
void fine_scatter(const int* __restrict__ rowptr,
                  const unsigned* __restrict__ scratch,
                  int* __restrict__ csr_src)
{
    __shared__ int lcur[256];
    const int tid = threadIdx.x;
    const int b   = blockIdx.x;
    const int nb  = b * 256;
    const int nn  = min(256, N_NODES - nb);
    if (tid < nn) lcur[tid] = rowptr[nb + tid];
    const int gb  = rowptr[nb];
    const int ge  = rowptr[nb + nn];
    __syncthreads();
    for (int i = gb + tid; i < ge; i += 256) {
        unsigned v = scratch[i];
        int p = atomicAdd(&lcur[v & 255u], 1);
        csr_src[p] = (int)(v >> 8);
    }
}

// ---------------- GEMM + alpha epilogue (layer 1, 32 rows/block) ------------
template<int CIN, bool DYN>
__global__ __launch_bounds__(256)
void gemm_alpha(const void* __restrict__ x,
                const float* __restrict__ W,
                const float* __restrict__ a_src,
                const float* __restrict__ a_dst,
                const unsigned* __restrict__ flag,
                bf16* __restrict__ hb,
                float* __restrict__ as_out,
                float* __restrict__ ad_out)
{
    __shared__ float sW[CIN * 64];
    __shared__ float sx[32 * CIN];
    const bool isbf = DYN ? (*flag != 0u) : false;
    const int tid = threadIdx.x;
    const int col = tid & 63;
    const int wv  = tid >> 6;
    const int row0 = blockIdx.x * 32;

    for (int i = tid * 4; i < CIN * 64; i += 1024)
        *(float4*)&sW[i] = *(const float4*)&W[i];

    const long xbase = (long)row0 * CIN;
    const int  tile  = 32 * CIN;
    const int  limit = (N_NODES - row0) * CIN;   // multiple of 4
    if (DYN && isbf) {
        const unsigned short* xb = (const unsigned short*)x + xbase;
        for (int i = tid * 4; i < tile; i += 1024) {
            float4 v = {0.f, 0.f, 0.f, 0.f};
            if (i < limit) {
                ushort4 u = *(const ushort4*)&xb[i];
                v.x = bfbits(u.x); v.y = bfbits(u.y);
                v.z = bfbits(u.z); v.w = bfbits(u.w);
            }
            *(float4*)&sx[i] = v;
        }
    } else {
        const float* xf = (const float*)x + xbase;
        for (int i = tid * 4; i < tile; i += 1024) {
            float4 v = {0.f, 0.f, 0.f, 0.f};
            if (i < limit) v = *(const float4*)&xf[i];
            *(float4*)&sx[i] = v;
        }
    }
    __syncthreads();

    const int rbase = wv * 8;
    float acc[8];
#pragma unroll
    for (int r = 0; r < 8; ++r) acc[r] = 0.f;

#pragma unroll 2
    for (int kk = 0; kk < CIN; kk += 4) {
        float w0 = sW[(kk + 0) * 64 + col];
        float w1 = sW[(kk + 1) * 64 + col];
        float w2 = sW[(kk + 2) * 64 + col];
        float w3 = sW[(kk + 3) * 64 + col];
#pragma unroll
        for (int r = 0; r < 8; ++r) {
            const float4 xv = *(const float4*)&sx[(rbase + r) * CIN + kk];
            acc[r] = fmaf(xv.x, w0,
                     fmaf(xv.y, w1,
                     fmaf(xv.z, w2,
                     fmaf(xv.w, w3, acc[r]))));
        }
    }

    const float sa = a_src[col];
    const float sd = a_dst[col];
#pragma unroll
    for (int r = 0; r < 8; ++r) {
        int row = row0 + rbase + r;
        float vs = acc[r] * sa;
        float vd = acc[r] * sd;
#pragma unroll
        for (int off = 32; off > 0; off >>= 1) {
            vs += __shfl_xor(vs, off, 64);
            vd += __shfl_xor(vd, off, 64);
        }
        if (row < N_NODES) {
            hb[(long)row * 64 + col] = __float2bfloat16(acc[r]);
            if (col == 0) { as_out[row] = vs; ad_out[row] = vd; }
        }
    }
}

// ============ gather core (no-max softmax: w & sum fused in one pass) =======
// 16-lane group per node. Returns a0..a7 (unnormalized) and dsum for channels
// c8..c8+7 on lanes with sub==0 (after xor-8 combine).
#define GATHER_NODE(node)                                                      \
    int beg = rowptr[node];                                                    \
    int deg = rowptr[node + 1] - beg;                                          \
    float adv = ad_in[node];                                                   \
    int   my_src = 0; float my_w = 0.f;                                        \
    if (l16 < deg) {                                                           \
        my_src = csr_src[beg + l16];                                           \
        float v = as_in[my_src] + adv;                                         \
        v = (v > 0.f) ? v : NEG_SLOPE * v;                                     \
        my_w = __expf(fminf(v, 60.f));                                         \
    }                                                                          \
    float a0=0.f,a1=0.f,a2=0.f,a3=0.f,a4=0.f,a5=0.f,a6=0.f,a7=0.f,dsum=0.f;   \
    const int dmin = (deg < 16) ? deg : 16;                                    \
    for (int j0 = 0; j0 < dmin; j0 += 2) {                                     \
        int j = j0 + sub;                                                      \
        float wj = __shfl(my_w, gb16 + j, 64);                                 \
        int   sj = __shfl(my_src, gb16 + j, 64);                               \
        if (j < dmin) {                                                        \
            const uint4 p = *(const uint4*)&hb_in[(long)sj * 64 + c8];         \
            a0 = fmaf(wj, bflo(p.x), a0); a1 = fmaf(wj, bfhi(p.x), a1);        \
            a2 = fmaf(wj, bflo(p.y), a2); a3 = fmaf(wj, bfhi(p.y), a3);        \
            a4 = fmaf(wj, bflo(p.z), a4); a5 = fmaf(wj, bfhi(p.z), a5);        \
            a6 = fmaf(wj, bflo(p.w), a6); a7 = fmaf(wj, bfhi(p.w), a7);        \
            dsum += wj;                                                        \
        }                                                                      \
    }                                                                          \
    for (int j0 = 16; j0 < deg; j0 += 2) {                                     \
        int j = j0 + sub;                                                      \
        if (j < deg) {                                                         \
            int sj = csr_src[beg + j];                                         \
            float v = as_in[sj] + adv;                                         \
            v = (v > 0.f) ? v : NEG_SLOPE * v;                                 \
            float wj = __expf(fminf(v, 60.f));                                 \
            const uint4 p = *(const uint4*)&hb_in[(long)sj * 64 + c8];         \
            a0 = fmaf(wj, bflo(p.x), a0); a1 = fmaf(wj, bfhi(p.x), a1);        \
            a2 = fmaf(wj, bflo(p.y), a2); a3 = fmaf(wj, bfhi(p.y), a3);        \
            a4 = fmaf(wj, bflo(p.z), a4); a5 = fmaf(wj, bfhi(p.z), a5);        \
            a6 = fmaf(wj, bflo(p.w), a6); a7 = fmaf(wj, bfhi(p.w), a7);        \
            dsum += wj;                                                        \
        }                                                                      \
    }                                                                          \
    a0 += __shfl_xor(a0, 8, 64); a1 += __shfl_xor(a1, 8, 64);                  \
    a2 += __shfl_xor(a2, 8, 64); a3 += __shfl_xor(a3, 8, 64);                  \
    a4 += __shfl_xor(a4, 8, 64); a5 += __shfl_xor(a5, 8, 64);                  \
    a6 += __shfl_xor(a6, 8, 64); a7 += __shfl_xor(a7, 8, 64);                  \
    dsum += __shfl_xor(dsum, 8, 64);

// ---------------- Fused: gather(layer l) + ELU + GEMM(layer l+1) ------------
// Block = 32 nodes. Gather writes ELU(out) rows to LDS; barrier; 32x64 GEMM
// against W(l+1) staged in LDS (staged before gather -> prefetch overlap).
__global__ __launch_bounds__(256)
void fused_gather_gemm(const int* __restrict__ rowptr,
                       const int* __restrict__ csr_src,
                       const float* __restrict__ as_in,
                       const float* __restrict__ ad_in,
                       const unsigned short* __restrict__ hb_in,
                       const float* __restrict__ bias_in,   // layer l bias
                       const float* __restrict__ W,         // layer l+1 (64x64)
                       const float* __restrict__ a_src,     // layer l+1
                       const float* __restrict__ a_dst,
                       bf16* __restrict__ hb_out,
                       float* __restrict__ as_out,
                       float* __restrict__ ad_out)
{
    __shared__ float sW[64 * 64];
    __shared__ float sx[32 * 64];

    const int tid  = threadIdx.x;
    const int lane = tid & 63;
    const int l16  = lane & 15;
    const int gb16 = lane & 48;
    const int grp  = tid >> 4;            // 0..15
    const int sub  = l16 >> 3;
    const int c8   = (l16 & 7) * 8;
    const int node0 = blockIdx.x * 32;

    // stage W(l+1) early — completes during the gather
    for (int i = tid * 4; i < 64 * 64; i += 1024)
        *(float4*)&sW[i] = *(const float4*)&W[i];

#pragma unroll
    for (int it = 0; it < 2; ++it) {
        int lnode = grp + 16 * it;
        int node  = node0 + lnode;
        if (node < N_NODES) {
            GATHER_NODE(node)
            if (sub == 0) {
                float inv = 1.f / dsum;
                float r[8] = {a0, a1, a2, a3, a4, a5, a6, a7};
#pragma unroll
                for (int k = 0; k < 8; ++k) {
                    r[k] = r[k] * inv + bias_in[c8 + k];
                    r[k] = (r[k] > 0.f) ? r[k] : expm1f(r[k]);   // ELU
                }
                float4 f0 = {r[0], r[1], r[2], r[3]};
                float4 f1 = {r[4], r[5], r[6], r[7]};
                *(float4*)&sx[lnode * 64 + c8]     = f0;
                *(float4*)&sx[lnode * 64 + c8 + 4] = f1;
            }
        }
    }
    __syncthreads();

    // ---- GEMM: 32 rows x 64, rows from LDS ----
    const int col = lane;
    const int wv  = tid >> 6;
    const int rbase = wv * 8;
    float acc[8];
#pragma unroll
    for (int r = 0; r < 8; ++r) acc[r] = 0.f;

#pragma unroll 2
    for (int kk = 0; kk < 64; kk += 4) {
        float w0 = sW[(kk + 0) * 64 + col];
        float w1 = sW[(kk + 1) * 64 + col];
        float w2 = sW[(kk + 2) * 64 + col];
        float w3 = sW[(kk + 3) * 64 + col];
#pragma unroll
        for (int r = 0; r < 8; ++r) {
            const float4 xv = *(const float4*)&sx[(rbase + r) * 64 + kk];
            acc[r] = fmaf(xv.x, w0,
                     fmaf(xv.y, w1,
                     fmaf(xv.z, w2,
                     fmaf(xv.w, w3, acc[r]))));
        }
    }

    const float sa = a_src[col];
    const float sd = a_dst[col];
#pragma unroll
    for (int r = 0; r < 8; ++r) {
        int row = node0 + rbase + r;
        float vs = acc[r] * sa;
        float vd = acc[r] * sd;
#pragma unroll
        for (int off = 32; off > 0; off >>= 1) {
            vs += __shfl_xor(vs, off, 64);
            vd += __shfl_xor(vd, off, 64);
        }
        if (row < N_NODES) {
            hb_out[(long)row * 64 + col] = __float2bfloat16(acc[r]);
            if (col == 0) { as_out[row] = vs; ad_out[row] = vd; }
        }
    }
}

// ---------------- Final gather (layer 3): bias, no ELU, dual-dtype out ------
__global__ __launch_bounds__(256)
void gat_out(const int* __restrict__ rowptr,
             const int* __restrict__ csr_src,
             const float* __restrict__ as_in,
             const float* __restrict__ ad_in,
             const unsigned short* __restrict__ hb_in,
             const float* __restrict__ bias,
             void* __restrict__ out,
             const unsigned* __restrict__ flag)
{
    const int tid  = threadIdx.x;
    const int lane = tid & 63;
    const int l16  = lane & 15;
    const int gb16 = lane & 48;
    const int grp  = tid >> 4;
    const int sub  = l16 >> 3;
    const int c8   = (l16 & 7) * 8;
    const int node0 = blockIdx.x * 32;

#pragma unroll
    for (int it = 0; it < 2; ++it) {
        int node = node0 + grp + 16 * it;
        if (node < N_NODES) {
            GATHER_NODE(node)
            if (sub == 0) {
                float inv = 1.f / dsum;
                float r[8] = {a0, a1, a2, a3, a4, a5, a6, a7};
#pragma unroll
                for (int k = 0; k < 8; ++k)
                    r[k] = r[k] * inv + bias[c8 + k];
                long o = (long)node * 64 + c8;
                if (*flag != 0u) {
                    uint4 u;
                    u.x = ((unsigned)__bfloat16_as_ushort(__float2bfloat16(r[0]))) |
                          (((unsigned)__bfloat16_as_ushort(__float2bfloat16(r[1]))) << 16);
                    u.y = ((unsigned)__bfloat16_as_ushort(__float2bfloat16(r[2]))) |
                          (((unsigned)__bfloat16_as_ushort(__float2bfloat16(r[3]))) << 16);
                    u.z = ((unsigned)__bfloat16_as_ushort(__float2bfloat16(r[4]))) |
                          (((unsigned)__bfloat16_as_ushort(__float2bfloat16(r[5]))) << 16);
                    u.w = ((unsigned)__bfloat16_as_ushort(__float2bfloat16(r[6]))) |
                          (((unsigned)__bfloat16_as_ushort(__float2bfloat16(r[7]))) << 16);
                    *(uint4*)&((unsigned short*)out)[o] = u;
                } else {
                    float4 f0 = {r[0], r[1], r[2], r[3]};
                    float4 f1 = {r[4], r[5], r[6], r[7]};
                    *(float4*)&((float*)out)[o]     = f0;
                    *(float4*)&((float*)out)[o + 4] = f1;
                }
            }
        }
    }
}

extern "C" void kernel_launch(void* const* d_in, const int* in_sizes, int n_in,
                              void* d_out, int out_size, void* d_ws, size_t ws_size,
                              hipStream_t stream)
{
    const void* x  = d_in[0];
    const int*  ei = (const int*)d_in[1];
    const void* pW1 = d_in[2],  *pas1 = d_in[3],  *pad1 = d_in[4],  *pb1 = d_in[5];
    const void* pW2 = d_in[6],  *pas2 = d_in[7],  *pad2 = d_in[8],  *pb2 = d_in[9];
    const void* pW3 = d_in[10], *pas3 = d_in[11], *pad3 = d_in[12], *pb3 = d_in[13];

    float* ws = (float*)d_ws;
    bf16*     hbA    = (bf16*)ws;                         // N*64 bf16
    bf16*     hbB    = (bf16*)(ws + (long)N_NODES * 32);  // N*64 bf16
    unsigned* scratch= (unsigned*)(ws + (long)N_NODES * 64);
    int*      csr_src= (int*)(scratch + ET_EDGES);
    float*    asA    = (float*)(csr_src + ET_EDGES);
    float*    adA    = asA + N_NODES;
    float*    asB    = adA + N_NODES;
    float*    adB    = asB + N_NODES;
    int*      deg    = (int*)(adB + N_NODES);
    int*      rowptr = deg + N_NODES;                     // N+1
    int*      bsum   = rowptr + N_NODES + 1;              // NBLK
    int*      cur256 = bsum + NBLK;                       // NBUCK
    float*    prm    = (float*)(cur256 + NBUCK);
    unsigned* flag   = (unsigned*)(prm + 20000);

    float* W1 = prm;     float* as1 = W1 + 8192; float* ad1 = as1 + 64; float* b1 = ad1 + 64;
    float* W2 = b1 + 64; float* as2 = W2 + 4096; float* ad2 = as2 + 64; float* b2 = ad2 + 64;
    float* W3 = b2 + 64; float* as3 = W3 + 4096; float* ad3 = as3 + 64; float* b3 = ad3 + 64;

    detect_dtype<<<1, 64, 0, stream>>>((const unsigned short*)pW1, flag);

    CvtArgs ca;
    const void* srcs[12] = {pW1, pas1, pad1, pb1, pW2, pas2, pad2, pb2, pW3, pas3, pad3, pb3};
    float*      dsts[12] = {W1, as1, ad1, b1, W2, as2, ad2, b2, W3, as3, ad3, b3};
    int         ns[12]   = {8192, 64, 64, 64, 4096, 64, 64, 64, 4096, 64, 64, 64};
    for (int i = 0; i < 12; ++i) { ca.src[i] = srcs[i]; ca.dst[i] = dsts[i]; ca.n[i] = ns[i]; }
    convert_params<<<dim3(8, 12), 256, 0, stream>>>(ca, flag);

    // ---- CSR build: hist -> rowptr -> bucket-binned two-pass scatter ----
    const int edge_grid = (ET_EDGES + 255) / 256;
    hipMemsetAsync(deg, 0, (size_t)N_NODES * 4, stream);
    edge_hist<<<edge_grid, 256, 0, stream>>>(ei, deg);
    scan1<<<NBLK, 256, 0, stream>>>(deg, bsum);
    scan2<<<1, 256, 0, stream>>>(bsum);
    scan3<<<NBLK, 256, 0, stream>>>(deg, bsum, rowptr, cur256);
    binpass<<<(ET_EDGES + CHUNK - 1) / CHUNK, 256, 0, stream>>>(ei, cur256, scratch);
    fine_scatter<<<NBUCK, 256, 0, stream>>>(rowptr, scratch, csr_src);

    const int gemm_grid = (N_NODES + 31) / 32;
    const int gat_grid  = (N_NODES + 31) / 32;

    // Layer 1 GEMM: x -> hbA, alphas(1) -> asA/adA
    gemm_alpha<128, true><<<gemm_grid, 256, 0, stream>>>(
        x, W1, as1, ad1, flag, hbA, asA, adA);

    // Fused: gather(1)+ELU+b1, GEMM W2 -> hbB, alphas(2) -> asB/adB
    fused_gather_gemm<<<gat_grid, 256, 0, stream>>>(
        rowptr, csr_src, asA, adA, (const unsigned short*)hbA, b1,
        W2, as2, ad2, hbB, asB, adB);

    // Fused: gather(2)+ELU+b2, GEMM W3 -> hbA, alphas(3) -> asA/adA
    fused_gather_gemm<<<gat_grid, 256, 0, stream>>>(
        rowptr, csr_src, asB, adB, (const unsigned short*)hbB, b2,
        W3, as3, ad3, hbA, asA, adA);

    // Final gather(3) + b3 -> d_out
    gat_out<<<gat_grid, 256, 0, stream>>>(
        rowptr, csr_src, asA, adA, (const unsigned short*)hbA, b3, d_out, flag);
}

// Round 10
// 334.097 us; speedup vs baseline: 1.0315x; 1.0315x over previous
//
#include <hip/hip_runtime.h>
#include <hip/hip_bf16.h>
#include <math.h>

#define N_NODES 50000
#define N_EDGES 800000
#define ET_EDGES (N_EDGES + N_NODES)   // with self-loops
#define NEG_SLOPE 0.2f
#define NBLK ((N_NODES + 255) / 256)   // 196 scan blocks
#define NBUCK ((N_NODES + 255) / 256)  // 196 dst buckets (256 nodes each)
#define CHUNK 4096                      // edges per binning block

typedef __hip_bfloat16 bf16;

__device__ inline float bfbits(unsigned short u) {
    return __uint_as_float(((unsigned)u) << 16);
}
__device__ inline float bflo(unsigned u) { return __uint_as_float(u << 16); }
__device__ inline float bfhi(unsigned u) { return __uint_as_float(u & 0xffff0000u); }

// ---------------- dtype detection ----------------
__global__ void detect_dtype(const unsigned short* __restrict__ w1raw,
                             unsigned* __restrict__ flag)
{
    int t = threadIdx.x;
    float v0 = bfbits(w1raw[2 * t]);
    float v1 = bfbits(w1raw[2 * t + 1]);
    bool bad = !(fabsf(v0) <= 64.f && fabsf(v1) <= 64.f);  // NaN -> bad
    unsigned long long b = __ballot(bad);
    if (t == 0) *flag = (b == 0ull) ? 1u : 0u;
}

// ---------------- param conversion (12 small tensors -> fp32) ----------------
struct CvtArgs {
    const void* src[12];
    float*      dst[12];
    int         n[12];
};

__global__ __launch_bounds__(256)
void convert_params(CvtArgs a, const unsigned* __restrict__ flag)
{
    bool isbf = (*flag != 0u);
    int which = blockIdx.y;
    int n = a.n[which];
    const void* s = a.src[which];
    float* d = a.dst[which];
    for (int i = blockIdx.x * 256 + threadIdx.x; i < n; i += gridDim.x * 256) {
        d[i] = isbf ? bfbits(((const unsigned short*)s)[i])
                    : ((const float*)s)[i];
    }
}

// ---------------- CSR build: degree histogram + rowptr scan ----------------
__global__ __launch_bounds__(256)
void edge_hist(const int* __restrict__ ei, int* __restrict__ deg)
{
    int e = blockIdx.x * 256 + threadIdx.x;
    if (e >= ET_EDGES) return;
    int d = (e < N_EDGES) ? ei[N_EDGES + e] : e - N_EDGES;
    atomicAdd(&deg[d], 1);
}

__global__ __launch_bounds__(256)
void scan1(const int* __restrict__ deg, int* __restrict__ bsum)
{
    __shared__ int s[256];
    int i = blockIdx.x * 256 + threadIdx.x;
    s[threadIdx.x] = (i < N_NODES) ? deg[i] : 0;
    __syncthreads();
    for (int off = 128; off > 0; off >>= 1) {
        if (threadIdx.x < off) s[threadIdx.x] += s[threadIdx.x + off];
        __syncthreads();
    }
    if (threadIdx.x == 0) bsum[blockIdx.x] = s[0];
}

__global__ __launch_bounds__(256)
void scan2(int* __restrict__ bsum)
{
    __shared__ int s[256];
    int t = threadIdx.x;
    int v = (t < NBLK) ? bsum[t] : 0;
    s[t] = v;
    __syncthreads();
    for (int off = 1; off < 256; off <<= 1) {
        int u = (t >= off) ? s[t - off] : 0;
        __syncthreads();
        s[t] += u;
        __syncthreads();
    }
    if (t < NBLK) bsum[t] = s[t] - v;   // exclusive
}

__global__ __launch_bounds__(256)
void scan3(const int* __restrict__ deg, const int* __restrict__ bsum,
           int* __restrict__ rowptr, int* __restrict__ cur256)
{
    __shared__ int s[256];
    int i = blockIdx.x * 256 + threadIdx.x;
    int v = (i < N_NODES) ? deg[i] : 0;
    s[threadIdx.x] = v;
    __syncthreads();
    for (int off = 1; off < 256; off <<= 1) {
        int t = (threadIdx.x >= off) ? s[threadIdx.x - off] : 0;
        __syncthreads();
        s[threadIdx.x] += t;
        __syncthreads();
    }
    if (i < N_NODES) {
        int excl = s[threadIdx.x] - v + bsum[blockIdx.x];
        rowptr[i] = excl;
        if (threadIdx.x == 0) cur256[blockIdx.x] = excl;  // bucket cursor base
    }
    if (i == 0) rowptr[N_NODES] = ET_EDGES;
}

// ---------------- Pass C: bin edges by dst bucket into scratch --------------
__global__ __launch_bounds__(256)
void binpass(const int* __restrict__ ei, int* __restrict__ cur256,
             unsigned* __restrict__ scratch)
{
    __shared__ int hist[NBUCK];
    __shared__ int lpre[NBUCK + 1];
    __shared__ int lcur[NBUCK];
    __shared__ int gbase[NBUCK];
    __shared__ int scan_a[256];
    __shared__ unsigned entry[CHUNK];

    const int tid = threadIdx.x;
    const int e0  = blockIdx.x * CHUNK;
    const int n   = min(CHUNK, ET_EDGES - e0);

    if (tid < NBUCK) hist[tid] = 0;
    __syncthreads();

    for (int k = tid; k < n; k += 256) {
        int e = e0 + k;
        int d = (e < N_EDGES) ? ei[N_EDGES + e] : e - N_EDGES;
        atomicAdd(&hist[d >> 8], 1);
    }
    __syncthreads();

    int v = (tid < NBUCK) ? hist[tid] : 0;
    scan_a[tid] = v;
    __syncthreads();
    for (int off = 1; off < 256; off <<= 1) {
        int t = (tid >= off) ? scan_a[tid - off] : 0;
        __syncthreads();
        scan_a[tid] += t;
        __syncthreads();
    }
    if (tid < NBUCK) lpre[tid] = scan_a[tid] - v;
    if (tid == NBUCK - 1) lpre[NBUCK] = scan_a[tid];
    if (tid < NBUCK) {
        gbase[tid] = v ? atomicAdd(&cur256[tid], v) : 0;
        lcur[tid] = 0;
    }
    __syncthreads();

    for (int k = tid; k < n; k += 256) {
        int e = e0 + k;
        int s, d;
        if (e < N_EDGES) { s = ei[e]; d = ei[N_EDGES + e]; }
        else             { s = d = e - N_EDGES; }
        int b = d >> 8;
        int p = atomicAdd(&lcur[b], 1);
        entry[lpre[b] + p] = ((unsigned)s << 8) | (unsigned)(d & 255);
    }
    __syncthreads();

    for (int i = tid; i < n; i += 256) {
        int lo = 0, hi = NBUCK;
        while (hi - lo > 1) {
            int mid = (lo + hi) >> 1;
            if (lpre[mid] <= i) lo = mid; else hi = mid;
        }
        scratch[gbase[lo] + (i - lpre[lo])] = entry[i];
    }
}

// ---------------- Pass D: fine scatter within each bucket -------------------
__global__ __launch_bounds__(256)
void fine_scatter(const int* __restrict__ rowptr,
                  const unsigned* __restrict__ scratch,
                  int* __restrict__ csr_src)
{
    __shared__ int lcur[256];
    const int tid = threadIdx.x;
    const int b   = blockIdx.x;
    const int nb  = b * 256;
    const int nn  = min(256, N_NODES - nb);
    if (tid < nn) lcur[tid] = rowptr[nb + tid];
    const int gb  = rowptr[nb];
    const int ge  = rowptr[nb + nn];
    __syncthreads();
    for (int i = gb + tid; i < ge; i += 256) {
        unsigned v = scratch[i];
        int p = atomicAdd(&lcur[v & 255u], 1);
        csr_src[p] = (int)(v >> 8);
    }
}

// ---------------- GEMM + alpha epilogue (32 rows/block, 8 rows/thread) ------
template<int CIN, bool DYN>
__global__ __launch_bounds__(256)
void gemm_alpha(const void* __restrict__ x,
                const float* __restrict__ W,
                const float* __restrict__ a_src,
                const float* __restrict__ a_dst,
                const unsigned* __restrict__ flag,
                bf16* __restrict__ hb,
                float* __restrict__ as_out,
                float* __restrict__ ad_out)
{
    __shared__ float sW[CIN * 64];
    __shared__ float sx[32 * CIN];
    const bool isbf = DYN ? (*flag != 0u) : false;
    const int tid = threadIdx.x;
    const int col = tid & 63;
    const int wv  = tid >> 6;
    const int row0 = blockIdx.x * 32;

    for (int i = tid * 4; i < CIN * 64; i += 1024)
        *(float4*)&sW[i] = *(const float4*)&W[i];

    const long xbase = (long)row0 * CIN;
    const int  tile  = 32 * CIN;
    const int  limit = (N_NODES - row0) * CIN;   // multiple of 4
    if (DYN && isbf) {
        const unsigned short* xb = (const unsigned short*)x + xbase;
        for (int i = tid * 4; i < tile; i += 1024) {
            float4 v = {0.f, 0.f, 0.f, 0.f};
            if (i < limit) {
                ushort4 u = *(const ushort4*)&xb[i];
                v.x = bfbits(u.x); v.y = bfbits(u.y);
                v.z = bfbits(u.z); v.w = bfbits(u.w);
            }
            *(float4*)&sx[i] = v;
        }
    } else {
        const float* xf = (const float*)x + xbase;
        for (int i = tid * 4; i < tile; i += 1024) {
            float4 v = {0.f, 0.f, 0.f, 0.f};
            if (i < limit) v = *(const float4*)&xf[i];
            *(float4*)&sx[i] = v;
        }
    }
    __syncthreads();

    const int rbase = wv * 8;
    float acc[8];
#pragma unroll
    for (int r = 0; r < 8; ++r) acc[r] = 0.f;

#pragma unroll 2
    for (int kk = 0; kk < CIN; kk += 4) {
        float w0 = sW[(kk + 0) * 64 + col];
        float w1 = sW[(kk + 1) * 64 + col];
        float w2 = sW[(kk + 2) * 64 + col];
        float w3 = sW[(kk + 3) * 64 + col];
#pragma unroll
        for (int r = 0; r < 8; ++r) {
            const float4 xv = *(const float4*)&sx[(rbase + r) * CIN + kk];
            acc[r] = fmaf(xv.x, w0,
                     fmaf(xv.y, w1,
                     fmaf(xv.z, w2,
                     fmaf(xv.w, w3, acc[r]))));
        }
    }

    const float sa = a_src[col];
    const float sd = a_dst[col];
#pragma unroll
    for (int r = 0; r < 8; ++r) {
        int row = row0 + rbase + r;
        float vs = acc[r] * sa;
        float vd = acc[r] * sd;
#pragma unroll
        for (int off = 32; off > 0; off >>= 1) {
            vs += __shfl_xor(vs, off, 64);
            vd += __shfl_xor(vd, off, 64);
        }
        if (row < N_NODES) {
            hb[(long)row * 64 + col] = __float2bfloat16(acc[r]);
            if (col == 0) { as_out[row] = vs; ad_out[row] = vd; }
        }
    }
}

// ---------------- GAT gather: 16-lane group/node, no-max softmax ------------
// Softmax is shift-invariant; scores |as+ad| are O(10) here so exp can't
// overflow fp32 (clamp 60 as seatbelt). One pass: w computed inline, dsum
// accumulated alongside the weighted sum — no max loop, no separate exp pass.
// 16 nodes/block (grid N/16 = 3125) keeps occupancy high for latency hiding
// (round 9 showed fusing this with GEMM halves blocks -> 29% occupancy, 1.5x slower).
template<bool DO_ELU, bool OUT_DYN>
__global__ __launch_bounds__(256)
void gat_gather(const int* __restrict__ rowptr,
                const int* __restrict__ csr_src,
                const float* __restrict__ as_in,
                const float* __restrict__ ad_in,
                const unsigned short* __restrict__ hb_in,
                const float* __restrict__ bias,
                void* __restrict__ out,
                const unsigned* __restrict__ flag)
{
    const int tid  = threadIdx.x;
    const int lane = tid & 63;
    const int l16  = lane & 15;
    const int gb16 = lane & 48;                    // group base within wave
    const int sub  = l16 >> 3;                     // edge slot 0/1
    const int c8   = (l16 & 7) * 8;                // channel group
    const int node = blockIdx.x * 16 + (tid >> 4); // 16 nodes per block
    if (node >= N_NODES) return;

    int beg = rowptr[node];
    int deg = rowptr[node + 1] - beg;
    float adv = ad_in[node];

    // first 16 edges: src + unnormalized weight in registers
    int   my_src = 0;
    float my_w   = 0.f;
    if (l16 < deg) {
        my_src = csr_src[beg + l16];
        float v = as_in[my_src] + adv;
        v = (v > 0.f) ? v : NEG_SLOPE * v;
        my_w = __expf(fminf(v, 60.f));
    }

    float a0=0.f,a1=0.f,a2=0.f,a3=0.f,a4=0.f,a5=0.f,a6=0.f,a7=0.f,dsum=0.f;
    const int dmin = (deg < 16) ? deg : 16;
    for (int j0 = 0; j0 < dmin; j0 += 2) {
        int j = j0 + sub;
        float wj = __shfl(my_w, gb16 + j, 64);
        int   sj = __shfl(my_src, gb16 + j, 64);
        if (j < dmin) {
            const uint4 p = *(const uint4*)&hb_in[(long)sj * 64 + c8];
            a0 = fmaf(wj, bflo(p.x), a0); a1 = fmaf(wj, bfhi(p.x), a1);
            a2 = fmaf(wj, bflo(p.y), a2); a3 = fmaf(wj, bfhi(p.y), a3);
            a4 = fmaf(wj, bflo(p.z), a4); a5 = fmaf(wj, bfhi(p.z), a5);
            a6 = fmaf(wj, bflo(p.w), a6); a7 = fmaf(wj, bfhi(p.w), a7);
            dsum += wj;
        }
    }
    for (int j0 = 16; j0 < deg; j0 += 2) {   // tail: compute w inline
        int j = j0 + sub;
        if (j < deg) {
            int sj = csr_src[beg + j];
            float v = as_in[sj] + adv;
            v = (v > 0.f) ? v : NEG_SLOPE * v;
            float wj = __expf(fminf(v, 60.f));
            const uint4 p = *(const uint4*)&hb_in[(long)sj * 64 + c8];
            a0 = fmaf(wj, bflo(p.x), a0); a1 = fmaf(wj, bfhi(p.x), a1);
            a2 = fmaf(wj, bflo(p.y), a2); a3 = fmaf(wj, bfhi(p.y), a3);
            a4 = fmaf(wj, bflo(p.z), a4); a5 = fmaf(wj, bfhi(p.z), a5);
            a6 = fmaf(wj, bflo(p.w), a6); a7 = fmaf(wj, bfhi(p.w), a7);
            dsum += wj;
        }
    }
    // combine the two edge slots
    a0 += __shfl_xor(a0, 8, 64); a1 += __shfl_xor(a1, 8, 64);
    a2 += __shfl_xor(a2, 8, 64); a3 += __shfl_xor(a3, 8, 64);
    a4 += __shfl_xor(a4, 8, 64); a5 += __shfl_xor(a5, 8, 64);
    a6 += __shfl_xor(a6, 8, 64); a7 += __shfl_xor(a7, 8, 64);
    dsum += __shfl_xor(dsum, 8, 64);

    if (sub == 0) {   // lanes l16 0..7 hold channels c8..c8+7
        float inv = 1.f / dsum;
        float r[8] = {a0, a1, a2, a3, a4, a5, a6, a7};
#pragma unroll
        for (int k = 0; k < 8; ++k) {
            r[k] = r[k] * inv + bias[c8 + k];
            if (DO_ELU) r[k] = (r[k] > 0.f) ? r[k] : expm1f(r[k]);
        }
        long o = (long)node * 64 + c8;
        if (OUT_DYN && *flag != 0u) {
            uint4 u;
            u.x = ((unsigned)__bfloat16_as_ushort(__float2bfloat16(r[0]))) |
                  (((unsigned)__bfloat16_as_ushort(__float2bfloat16(r[1]))) << 16);
            u.y = ((unsigned)__bfloat16_as_ushort(__float2bfloat16(r[2]))) |
                  (((unsigned)__bfloat16_as_ushort(__float2bfloat16(r[3]))) << 16);
            u.z = ((unsigned)__bfloat16_as_ushort(__float2bfloat16(r[4]))) |
                  (((unsigned)__bfloat16_as_ushort(__float2bfloat16(r[5]))) << 16);
            u.w = ((unsigned)__bfloat16_as_ushort(__float2bfloat16(r[6]))) |
                  (((unsigned)__bfloat16_as_ushort(__float2bfloat16(r[7]))) << 16);
            *(uint4*)&((unsigned short*)out)[o] = u;
        } else {
            float4 f0 = {r[0], r[1], r[2], r[3]};
            float4 f1 = {r[4], r[5], r[6], r[7]};
            *(float4*)&((float*)out)[o]     = f0;
            *(float4*)&((float*)out)[o + 4] = f1;
        }
    }
}

extern "C" void kernel_launch(void* const* d_in, const int* in_sizes, int n_in,
                              void* d_out, int out_size, void* d_ws, size_t ws_size,
                              hipStream_t stream)
{
    const void* x  = d_in[0];
    const int*  ei = (const int*)d_in[1];
    const void* pW1 = d_in[2],  *pas1 = d_in[3],  *pad1 = d_in[4],  *pb1 = d_in[5];
    const void* pW2 = d_in[6],  *pas2 = d_in[7],  *pad2 = d_in[8],  *pb2 = d_in[9];
    const void* pW3 = d_in[10], *pas3 = d_in[11], *pad3 = d_in[12], *pb3 = d_in[13];

    float* ws = (float*)d_ws;
    float*    bufA   = ws;                          // hb bf16 lower, scratch upper
    float*    bufB   = bufA + (long)N_NODES * 64;   // layer io fp32     12.8 MB
    float*    as_    = bufB + (long)N_NODES * 64;
    float*    ad_    = as_ + N_NODES;
    int*      deg    = (int*)(ad_ + N_NODES);
    int*      rowptr = deg + N_NODES;               // N+1
    int*      bsum   = rowptr + N_NODES + 1;        // NBLK
    int*      cur256 = bsum + NBLK;                 // NBUCK
    int*      csr_src= cur256 + NBUCK;              // 3.4 MB
    float*    prm    = (float*)(csr_src + ET_EDGES);
    unsigned* flag   = (unsigned*)(prm + 20000);
    bf16*     hb     = (bf16*)bufA;
    unsigned* scratch= (unsigned*)(bufA + (long)N_NODES * 32);  // upper half of bufA

    float* W1 = prm;     float* as1 = W1 + 8192; float* ad1 = as1 + 64; float* b1 = ad1 + 64;
    float* W2 = b1 + 64; float* as2 = W2 + 4096; float* ad2 = as2 + 64; float* b2 = ad2 + 64;
    float* W3 = b2 + 64; float* as3 = W3 + 4096; float* ad3 = as3 + 64; float* b3 = ad3 + 64;

    detect_dtype<<<1, 64, 0, stream>>>((const unsigned short*)pW1, flag);

    CvtArgs ca;
    const void* srcs[12] = {pW1, pas1, pad1, pb1, pW2, pas2, pad2, pb2, pW3, pas3, pad3, pb3};
    float*      dsts[12] = {W1, as1, ad1, b1, W2, as2, ad2, b2, W3, as3, ad3, b3};
    int         ns[12]   = {8192, 64, 64, 64, 4096, 64, 64, 64, 4096, 64, 64, 64};
    for (int i = 0; i < 12; ++i) { ca.src[i] = srcs[i]; ca.dst[i] = dsts[i]; ca.n[i] = ns[i]; }
    convert_params<<<dim3(8, 12), 256, 0, stream>>>(ca, flag);

    // ---- CSR build: hist -> rowptr -> bucket-binned two-pass scatter ----
    const int edge_grid = (ET_EDGES + 255) / 256;
    hipMemsetAsync(deg, 0, (size_t)N_NODES * 4, stream);
    edge_hist<<<edge_grid, 256, 0, stream>>>(ei, deg);
    scan1<<<NBLK, 256, 0, stream>>>(deg, bsum);
    scan2<<<1, 256, 0, stream>>>(bsum);
    scan3<<<NBLK, 256, 0, stream>>>(deg, bsum, rowptr, cur256);
    binpass<<<(ET_EDGES + CHUNK - 1) / CHUNK, 256, 0, stream>>>(ei, cur256, scratch);
    fine_scatter<<<NBUCK, 256, 0, stream>>>(rowptr, scratch, csr_src);

    const int gemm_grid = (N_NODES + 31) / 32;
    const int gat_grid  = (N_NODES + 15) / 16;

    // ---------- Layer 1 ----------
    gemm_alpha<128, true><<<gemm_grid, 256, 0, stream>>>(
        x, W1, as1, ad1, flag, hb, as_, ad_);
    gat_gather<true, false><<<gat_grid, 256, 0, stream>>>(
        rowptr, csr_src, as_, ad_, (const unsigned short*)hb, b1, bufB, flag);

    // ---------- Layer 2 ----------
    gemm_alpha<64, false><<<gemm_grid, 256, 0, stream>>>(
        bufB, W2, as2, ad2, flag, hb, as_, ad_);
    gat_gather<true, false><<<gat_grid, 256, 0, stream>>>(
        rowptr, csr_src, as_, ad_, (const unsigned short*)hb, b2, bufB, flag);

    // ---------- Layer 3 ----------
    gemm_alpha<64, false><<<gemm_grid, 256, 0, stream>>>(
        bufB, W3, as3, ad3, flag, hb, as_, ad_);
    gat_gather<false, true><<<gat_grid, 256, 0, stream>>>(
        rowptr, csr_src, as_, ad_, (const unsigned short*)hb, b3, d_out, flag);
}

// Round 11
// 326.458 us; speedup vs baseline: 1.0556x; 1.0234x over previous
//
#include <hip/hip_runtime.h>
#include <hip/hip_bf16.h>
#include <math.h>

#define N_NODES 50000
#define N_EDGES 800000
#define ET_EDGES (N_EDGES + N_NODES)   // with self-loops
#define NEG_SLOPE 0.2f
#define NBLK ((N_NODES + 255) / 256)   // 196 scan blocks
#define NBUCK ((N_NODES + 255) / 256)  // 196 dst buckets (256 nodes each)
#define CHUNK 4096                      // edges per binning block

typedef __hip_bfloat16 bf16;

__device__ inline float bfbits(unsigned short u) {
    return __uint_as_float(((unsigned)u) << 16);
}
__device__ inline float bflo(unsigned u) { return __uint_as_float(u << 16); }
__device__ inline float bfhi(unsigned u) { return __uint_as_float(u & 0xffff0000u); }

// ---------------- dtype detection ----------------
__global__ void detect_dtype(const unsigned short* __restrict__ w1raw,
                             unsigned* __restrict__ flag)
{
    int t = threadIdx.x;
    float v0 = bfbits(w1raw[2 * t]);
    float v1 = bfbits(w1raw[2 * t + 1]);
    bool bad = !(fabsf(v0) <= 64.f && fabsf(v1) <= 64.f);  // NaN -> bad
    unsigned long long b = __ballot(bad);
    if (t == 0) *flag = (b == 0ull) ? 1u : 0u;
}

// ---------------- param conversion (12 small tensors -> fp32) ----------------
struct CvtArgs {
    const void* src[12];
    float*      dst[12];
    int         n[12];
};

__global__ __launch_bounds__(256)
void convert_params(CvtArgs a, const unsigned* __restrict__ flag)
{
    bool isbf = (*flag != 0u);
    int which = blockIdx.y;
    int n = a.n[which];
    const void* s = a.src[which];
    float* d = a.dst[which];
    for (int i = blockIdx.x * 256 + threadIdx.x; i < n; i += gridDim.x * 256) {
        d[i] = isbf ? bfbits(((const unsigned short*)s)[i])
                    : ((const float*)s)[i];
    }
}

// ---------------- CSR build: degree histogram + rowptr scan ----------------
__global__ __launch_bounds__(256)
void edge_hist(const int* __restrict__ ei, int* __restrict__ deg)
{
    int e = blockIdx.x * 256 + threadIdx.x;
    if (e >= ET_EDGES) return;
    int d = (e < N_EDGES) ? ei[N_EDGES + e] : e - N_EDGES;
    atomicAdd(&deg[d], 1);
}

__global__ __launch_bounds__(256)
void scan1(const int* __restrict__ deg, int* __restrict__ bsum)
{
    __shared__ int s[256];
    int i = blockIdx.x * 256 + threadIdx.x;
    s[threadIdx.x] = (i < N_NODES) ? deg[i] : 0;
    __syncthreads();
    for (int off = 128; off > 0; off >>= 1) {
        if (threadIdx.x < off) s[threadIdx.x] += s[threadIdx.x + off];
        __syncthreads();
    }
    if (threadIdx.x == 0) bsum[blockIdx.x] = s[0];
}

__global__ __launch_bounds__(256)
void scan2(int* __restrict__ bsum)
{
    __shared__ int s[256];
    int t = threadIdx.x;
    int v = (t < NBLK) ? bsum[t] : 0;
    s[t] = v;
    __syncthreads();
    for (int off = 1; off < 256; off <<= 1) {
        int u = (t >= off) ? s[t - off] : 0;
        __syncthreads();
        s[t] += u;
        __syncthreads();
    }
    if (t < NBLK) bsum[t] = s[t] - v;   // exclusive
}

__global__ __launch_bounds__(256)
void scan3(const int* __restrict__ deg, const int* __restrict__ bsum,
           int* __restrict__ rowptr, int* __restrict__ cur256)
{
    __shared__ int s[256];
    int i = blockIdx.x * 256 + threadIdx.x;
    int v = (i < N_NODES) ? deg[i] : 0;
    s[threadIdx.x] = v;
    __syncthreads();
    for (int off = 1; off < 256; off <<= 1) {
        int t = (threadIdx.x >= off) ? s[threadIdx.x - off] : 0;
        __syncthreads();
        s[threadIdx.x] += t;
        __syncthreads();
    }
    if (i < N_NODES) {
        int excl = s[threadIdx.x] - v + bsum[blockIdx.x];
        rowptr[i] = excl;
        if (threadIdx.x == 0) cur256[blockIdx.x] = excl;  // bucket cursor base
    }
    if (i == 0) rowptr[N_NODES] = ET_EDGES;
}

// ---------------- Pass C: bin edges by dst bucket into scratch --------------
__global__ __launch_bounds__(256)
void binpass(const int* __restrict__ ei, int* __restrict__ cur256,
             unsigned* __restrict__ scratch)
{
    __shared__ int hist[NBUCK];
    __shared__ int lpre[NBUCK + 1];
    __shared__ int lcur[NBUCK];
    __shared__ int gbase[NBUCK];
    __shared__ int scan_a[256];
    __shared__ unsigned entry[CHUNK];

    const int tid = threadIdx.x;
    const int e0  = blockIdx.x * CHUNK;
    const int n   = min(CHUNK, ET_EDGES - e0);

    if (tid < NBUCK) hist[tid] = 0;
    __syncthreads();

    for (int k = tid; k < n; k += 256) {
        int e = e0 + k;
        int d = (e < N_EDGES) ? ei[N_EDGES + e] : e - N_EDGES;
        atomicAdd(&hist[d >> 8], 1);
    }
    __syncthreads();

    int v = (tid < NBUCK) ? hist[tid] : 0;
    scan_a[tid] = v;
    __syncthreads();
    for (int off = 1; off < 256; off <<= 1) {
        int t = (tid >= off) ? scan_a[tid - off] : 0;
        __syncthreads();
        scan_a[tid] += t;
        __syncthreads();
    }
    if (tid < NBUCK) lpre[tid] = scan_a[tid] - v;
    if (tid == NBUCK - 1) lpre[NBUCK] = scan_a[tid];
    if (tid < NBUCK) {
        gbase[tid] = v ? atomicAdd(&cur256[tid], v) : 0;
        lcur[tid] = 0;
    }
    __syncthreads();

    for (int k = tid; k < n; k += 256) {
        int e = e0 + k;
        int s, d;
        if (e < N_EDGES) { s = ei[e]; d = ei[N_EDGES + e]; }
        else             { s = d = e - N_EDGES; }
        int b = d >> 8;
        int p = atomicAdd(&lcur[b], 1);
        entry[lpre[b] + p] = ((unsigned)s << 8) | (unsigned)(d & 255);
    }
    __syncthreads();

    for (int i = tid; i < n; i += 256) {
        int lo = 0, hi = NBUCK;
        while (hi - lo > 1) {
            int mid = (lo + hi) >> 1;
            if (lpre[mid] <= i) lo = mid; else hi = mid;
        }
        scratch[gbase[lo] + (i - lpre[lo])] = entry[i];
    }
}

// ---------------- Pass D: fine scatter within each bucket -------------------
__global__ __launch_bounds__(256)
void fine_scatter(const int* __restrict__ rowptr,
                  const unsigned* __restrict__ scratch,
                  int* __restrict__ csr_src)
{
    __shared__ int lcur[256];
    const int tid = threadIdx.x;
    const int b   = blockIdx.x;
    const int nb  = b * 256;
    const int nn  = min(256, N_NODES - nb);
    if (tid < nn) lcur[tid] = rowptr[nb + tid];
    const int gb  = rowptr[nb];
    const int ge  = rowptr[nb + nn];
    __syncthreads();
    for (int i = gb + tid; i < ge; i += 256) {
        unsigned v = scratch[i];
        int p = atomicAdd(&lcur[v & 255u], 1);
        csr_src[p] = (int)(v >> 8);
    }
}

// ---------------- GEMM + alpha epilogue (32 rows/block, 8 rows/thread) ------
template<int CIN, bool DYN>
__global__ __launch_bounds__(256)
void gemm_alpha(const void* __restrict__ x,
                const float* __restrict__ W,
                const float* __restrict__ a_src,
                const float* __restrict__ a_dst,
                const unsigned* __restrict__ flag,
                bf16* __restrict__ hb,
                float* __restrict__ as_out,
                float* __restrict__ ad_out)
{
    __shared__ float sW[CIN * 64];
    __shared__ float sx[32 * CIN];
    const bool isbf = DYN ? (*flag != 0u) : false;
    const int tid = threadIdx.x;
    const int col = tid & 63;
    const int wv  = tid >> 6;
    const int row0 = blockIdx.x * 32;

    for (int i = tid * 4; i < CIN * 64; i += 1024)
        *(float4*)&sW[i] = *(const float4*)&W[i];

    const long xbase = (long)row0 * CIN;
    const int  tile  = 32 * CIN;
    const int  limit = (N_NODES - row0) * CIN;   // multiple of 4
    if (DYN && isbf) {
        const unsigned short* xb = (const unsigned short*)x + xbase;
        for (int i = tid * 4; i < tile; i += 1024) {
            float4 v = {0.f, 0.f, 0.f, 0.f};
            if (i < limit) {
                ushort4 u = *(const ushort4*)&xb[i];
                v.x = bfbits(u.x); v.y = bfbits(u.y);
                v.z = bfbits(u.z); v.w = bfbits(u.w);
            }
            *(float4*)&sx[i] = v;
        }
    } else {
        const float* xf = (const float*)x + xbase;
        for (int i = tid * 4; i < tile; i += 1024) {
            float4 v = {0.f, 0.f, 0.f, 0.f};
            if (i < limit) v = *(const float4*)&xf[i];
            *(float4*)&sx[i] = v;
        }
    }
    __syncthreads();

    const int rbase = wv * 8;
    float acc[8];
#pragma unroll
    for (int r = 0; r < 8; ++r) acc[r] = 0.f;

#pragma unroll 2
    for (int kk = 0; kk < CIN; kk += 4) {
        float w0 = sW[(kk + 0) * 64 + col];
        float w1 = sW[(kk + 1) * 64 + col];
        float w2 = sW[(kk + 2) * 64 + col];
        float w3 = sW[(kk + 3) * 64 + col];
#pragma unroll
        for (int r = 0; r < 8; ++r) {
            const float4 xv = *(const float4*)&sx[(rbase + r) * CIN + kk];
            acc[r] = fmaf(xv.x, w0,
                     fmaf(xv.y, w1,
                     fmaf(xv.z, w2,
                     fmaf(xv.w, w3, acc[r]))));
        }
    }

    const float sa = a_src[col];
    const float sd = a_dst[col];
#pragma unroll
    for (int r = 0; r < 8; ++r) {
        int row = row0 + rbase + r;
        float vs = acc[r] * sa;
        float vd = acc[r] * sd;
#pragma unroll
        for (int off = 32; off > 0; off >>= 1) {
            vs += __shfl_xor(vs, off, 64);
            vd += __shfl_xor(vd, off, 64);
        }
        if (row < N_NODES) {
            hb[(long)row * 64 + col] = __float2bfloat16(acc[r]);
            if (col == 0) { as_out[row] = vs; ad_out[row] = vd; }
        }
    }
}

// ---------------- GAT gather: 16-lane group/node, no-max softmax ------------
// 32-edge register cache (2 edges/lane preloaded: src + exp-weight), so the
// per-edge recompute tail only triggers for deg>32 (P ~ 0.04% at mean deg 17).
// Main loop: 4 edges/iteration, two uint4 loads issued back-to-back for MLP.
// 16 nodes/block (grid 3125) keeps occupancy high (round 9: fusing with GEMM
// halved blocks -> 29% occupancy, 1.5x slower).
template<bool DO_ELU, bool OUT_DYN>
__global__ __launch_bounds__(256)
void gat_gather(const int* __restrict__ rowptr,
                const int* __restrict__ csr_src,
                const float* __restrict__ as_in,
                const float* __restrict__ ad_in,
                const unsigned short* __restrict__ hb_in,
                const float* __restrict__ bias,
                void* __restrict__ out,
                const unsigned* __restrict__ flag)
{
    const int tid  = threadIdx.x;
    const int lane = tid & 63;
    const int l16  = lane & 15;
    const int gb16 = lane & 48;                    // group base within wave
    const int sub  = l16 >> 3;                     // edge slot 0/1
    const int c8   = (l16 & 7) * 8;                // channel group
    const int node = blockIdx.x * 16 + (tid >> 4); // 16 nodes per block
    if (node >= N_NODES) return;

    const int beg = rowptr[node];
    const int deg = rowptr[node + 1] - beg;
    const float adv = ad_in[node];

    // preload up to 32 edges: 2 per lane (src + unnormalized weight)
    int   msrc0 = 0, msrc1 = 0;
    float mw0 = 0.f, mw1 = 0.f;
    if (l16 < deg) {
        msrc0 = csr_src[beg + l16];
        float v = as_in[msrc0] + adv;
        v = (v > 0.f) ? v : NEG_SLOPE * v;
        mw0 = __expf(fminf(v, 60.f));
    }
    if (16 + l16 < deg) {
        msrc1 = csr_src[beg + 16 + l16];
        float v = as_in[msrc1] + adv;
        v = (v > 0.f) ? v : NEG_SLOPE * v;
        mw1 = __expf(fminf(v, 60.f));
    }

    float a0=0.f,a1=0.f,a2=0.f,a3=0.f,a4=0.f,a5=0.f,a6=0.f,a7=0.f,dsum=0.f;
    const int lim = (deg < 32) ? deg : 32;

    // bank 0: edges 0..15 (j0 uniform per wave -> no divergent bank choice)
#pragma unroll
    for (int j0 = 0; j0 < 16; j0 += 4) {
        if (j0 >= lim) break;
        const int jA = j0 + sub;
        const int jB = j0 + 2 + sub;
        float wA = __shfl(mw0,  gb16 + jA, 64);
        int   sA = __shfl(msrc0, gb16 + jA, 64);
        float wB = __shfl(mw0,  gb16 + jB, 64);
        int   sB = __shfl(msrc0, gb16 + jB, 64);
        uint4 pA = {0u,0u,0u,0u}, pB = {0u,0u,0u,0u};
        const bool vA = jA < lim, vB = jB < lim;
        if (vA) pA = *(const uint4*)&hb_in[(long)sA * 64 + c8];
        if (vB) pB = *(const uint4*)&hb_in[(long)sB * 64 + c8];
        if (!vA) wA = 0.f;
        if (!vB) wB = 0.f;
        a0 = fmaf(wA, bflo(pA.x), a0); a1 = fmaf(wA, bfhi(pA.x), a1);
        a2 = fmaf(wA, bflo(pA.y), a2); a3 = fmaf(wA, bfhi(pA.y), a3);
        a4 = fmaf(wA, bflo(pA.z), a4); a5 = fmaf(wA, bfhi(pA.z), a5);
        a6 = fmaf(wA, bflo(pA.w), a6); a7 = fmaf(wA, bfhi(pA.w), a7);
        a0 = fmaf(wB, bflo(pB.x), a0); a1 = fmaf(wB, bfhi(pB.x), a1);
        a2 = fmaf(wB, bflo(pB.y), a2); a3 = fmaf(wB, bfhi(pB.y), a3);
        a4 = fmaf(wB, bflo(pB.z), a4); a5 = fmaf(wB, bfhi(pB.z), a5);
        a6 = fmaf(wB, bflo(pB.w), a6); a7 = fmaf(wB, bfhi(pB.w), a7);
        dsum += wA + wB;
    }
    // bank 1: edges 16..31
#pragma unroll
    for (int j0 = 16; j0 < 32; j0 += 4) {
        if (j0 >= lim) break;
        const int jA = j0 + sub;
        const int jB = j0 + 2 + sub;
        float wA = __shfl(mw1,  gb16 + jA - 16, 64);
        int   sA = __shfl(msrc1, gb16 + jA - 16, 64);
        float wB = __shfl(mw1,  gb16 + jB - 16, 64);
        int   sB = __shfl(msrc1, gb16 + jB - 16, 64);
        uint4 pA = {0u,0u,0u,0u}, pB = {0u,0u,0u,0u};
        const bool vA = jA < lim, vB = jB < lim;
        if (vA) pA = *(const uint4*)&hb_in[(long)sA * 64 + c8];
        if (vB) pB = *(const uint4*)&hb_in[(long)sB * 64 + c8];
        if (!vA) wA = 0.f;
        if (!vB) wB = 0.f;
        a0 = fmaf(wA, bflo(pA.x), a0); a1 = fmaf(wA, bfhi(pA.x), a1);
        a2 = fmaf(wA, bflo(pA.y), a2); a3 = fmaf(wA, bfhi(pA.y), a3);
        a4 = fmaf(wA, bflo(pA.z), a4); a5 = fmaf(wA, bfhi(pA.z), a5);
        a6 = fmaf(wA, bflo(pA.w), a6); a7 = fmaf(wA, bfhi(pA.w), a7);
        a0 = fmaf(wB, bflo(pB.x), a0); a1 = fmaf(wB, bfhi(pB.x), a1);
        a2 = fmaf(wB, bflo(pB.y), a2); a3 = fmaf(wB, bfhi(pB.y), a3);
        a4 = fmaf(wB, bflo(pB.z), a4); a5 = fmaf(wB, bfhi(pB.z), a5);
        a6 = fmaf(wB, bflo(pB.w), a6); a7 = fmaf(wB, bfhi(pB.w), a7);
        dsum += wA + wB;
    }
    // rare tail: deg > 32 (compute w inline)
    for (int j0 = 32; j0 < deg; j0 += 2) {
        const int j = j0 + sub;
        if (j < deg) {
            int sj = csr_src[beg + j];
            float v = as_in[sj] + adv;
            v = (v > 0.f) ? v : NEG_SLOPE * v;
            float wj = __expf(fminf(v, 60.f));
            const uint4 p = *(const uint4*)&hb_in[(long)sj * 64 + c8];
            a0 = fmaf(wj, bflo(p.x), a0); a1 = fmaf(wj, bfhi(p.x), a1);
            a2 = fmaf(wj, bflo(p.y), a2); a3 = fmaf(wj, bfhi(p.y), a3);
            a4 = fmaf(wj, bflo(p.z), a4); a5 = fmaf(wj, bfhi(p.z), a5);
            a6 = fmaf(wj, bflo(p.w), a6); a7 = fmaf(wj, bfhi(p.w), a7);
            dsum += wj;
        }
    }

    // combine the two edge slots
    a0 += __shfl_xor(a0, 8, 64); a1 += __shfl_xor(a1, 8, 64);
    a2 += __shfl_xor(a2, 8, 64); a3 += __shfl_xor(a3, 8, 64);
    a4 += __shfl_xor(a4, 8, 64); a5 += __shfl_xor(a5, 8, 64);
    a6 += __shfl_xor(a6, 8, 64); a7 += __shfl_xor(a7, 8, 64);
    dsum += __shfl_xor(dsum, 8, 64);

    if (sub == 0) {   // lanes l16 0..7 hold channels c8..c8+7
        float inv = 1.f / dsum;
        float r[8] = {a0, a1, a2, a3, a4, a5, a6, a7};
#pragma unroll
        for (int k = 0; k < 8; ++k) {
            r[k] = r[k] * inv + bias[c8 + k];
            if (DO_ELU) r[k] = (r[k] > 0.f) ? r[k] : expm1f(r[k]);
        }
        long o = (long)node * 64 + c8;
        if (OUT_DYN && *flag != 0u) {
            uint4 u;
            u.x = ((unsigned)__bfloat16_as_ushort(__float2bfloat16(r[0]))) |
                  (((unsigned)__bfloat16_as_ushort(__float2bfloat16(r[1]))) << 16);
            u.y = ((unsigned)__bfloat16_as_ushort(__float2bfloat16(r[2]))) |
                  (((unsigned)__bfloat16_as_ushort(__float2bfloat16(r[3]))) << 16);
            u.z = ((unsigned)__bfloat16_as_ushort(__float2bfloat16(r[4]))) |
                  (((unsigned)__bfloat16_as_ushort(__float2bfloat16(r[5]))) << 16);
            u.w = ((unsigned)__bfloat16_as_ushort(__float2bfloat16(r[6]))) |
                  (((unsigned)__bfloat16_as_ushort(__float2bfloat16(r[7]))) << 16);
            *(uint4*)&((unsigned short*)out)[o] = u;
        } else {
            float4 f0 = {r[0], r[1], r[2], r[3]};
            float4 f1 = {r[4], r[5], r[6], r[7]};
            *(float4*)&((float*)out)[o]     = f0;
            *(float4*)&((float*)out)[o + 4] = f1;
        }
    }
}

extern "C" void kernel_launch(void* const* d_in, const int* in_sizes, int n_in,
                              void* d_out, int out_size, void* d_ws, size_t ws_size,
                              hipStream_t stream)
{
    const void* x  = d_in[0];
    const int*  ei = (const int*)d_in[1];
    const void* pW1 = d_in[2],  *pas1 = d_in[3],  *pad1 = d_in[4],  *pb1 = d_in[5];
    const void* pW2 = d_in[6],  *pas2 = d_in[7],  *pad2 = d_in[8],  *pb2 = d_in[9];
    const void* pW3 = d_in[10], *pas3 = d_in[11], *pad3 = d_in[12], *pb3 = d_in[13];

    float* ws = (float*)d_ws;
    float*    bufA   = ws;                          // hb bf16 lower, scratch upper
    float*    bufB   = bufA + (long)N_NODES * 64;   // layer io fp32     12.8 MB
    float*    as_    = bufB + (long)N_NODES * 64;
    float*    ad_    = as_ + N_NODES;
    int*      deg    = (int*)(ad_ + N_NODES);
    int*      rowptr = deg + N_NODES;               // N+1
    int*      bsum   = rowptr + N_NODES + 1;        // NBLK
    int*      cur256 = bsum + NBLK;                 // NBUCK
    int*      csr_src= cur256 + NBUCK;              // 3.4 MB
    float*    prm    = (float*)(csr_src + ET_EDGES);
    unsigned* flag   = (unsigned*)(prm + 20000);
    bf16*     hb     = (bf16*)bufA;
    unsigned* scratch= (unsigned*)(bufA + (long)N_NODES * 32);  // upper half of bufA

    float* W1 = prm;     float* as1 = W1 + 8192; float* ad1 = as1 + 64; float* b1 = ad1 + 64;
    float* W2 = b1 + 64; float* as2 = W2 + 4096; float* ad2 = as2 + 64; float* b2 = ad2 + 64;
    float* W3 = b2 + 64; float* as3 = W3 + 4096; float* ad3 = as3 + 64; float* b3 = ad3 + 64;

    detect_dtype<<<1, 64, 0, stream>>>((const unsigned short*)pW1, flag);

    CvtArgs ca;
    const void* srcs[12] = {pW1, pas1, pad1, pb1, pW2, pas2, pad2, pb2, pW3, pas3, pad3, pb3};
    float*      dsts[12] = {W1, as1, ad1, b1, W2, as2, ad2, b2, W3, as3, ad3, b3};
    int         ns[12]   = {8192, 64, 64, 64, 4096, 64, 64, 64, 4096, 64, 64, 64};
    for (int i = 0; i < 12; ++i) { ca.src[i] = srcs[i]; ca.dst[i] = dsts[i]; ca.n[i] = ns[i]; }
    convert_params<<<dim3(8, 12), 256, 0, stream>>>(ca, flag);

    // ---- CSR build: hist -> rowptr -> bucket-binned two-pass scatter ----
    const int edge_grid = (ET_EDGES + 255) / 256;
    hipMemsetAsync(deg, 0, (size_t)N_NODES * 4, stream);
    edge_hist<<<edge_grid, 256, 0, stream>>>(ei, deg);
    scan1<<<NBLK, 256, 0, stream>>>(deg, bsum);
    scan2<<<1, 256, 0, stream>>>(bsum);
    scan3<<<NBLK, 256, 0, stream>>>(deg, bsum, rowptr, cur256);
    binpass<<<(ET_EDGES + CHUNK - 1) / CHUNK, 256, 0, stream>>>(ei, cur256, scratch);
    fine_scatter<<<NBUCK, 256, 0, stream>>>(rowptr, scratch, csr_src);

    const int gemm_grid = (N_NODES + 31) / 32;
    const int gat_grid  = (N_NODES + 15) / 16;

    // ---------- Layer 1 ----------
    gemm_alpha<128, true><<<gemm_grid, 256, 0, stream>>>(
        x, W1, as1, ad1, flag, hb, as_, ad_);
    gat_gather<true, false><<<gat_grid, 256, 0, stream>>>(
        rowptr, csr_src, as_, ad_, (const unsigned short*)hb, b1, bufB, flag);

    // ---------- Layer 2 ----------
    gemm_alpha<64, false><<<gemm_grid, 256, 0, stream>>>(
        bufB, W2, as2, ad2, flag, hb, as_, ad_);
    gat_gather<true, false><<<gat_grid, 256, 0, stream>>>(
        rowptr, csr_src, as_, ad_, (const unsigned short*)hb, b2, bufB, flag);

    // ---------- Layer 3 ----------
    gemm_alpha<64, false><<<gemm_grid, 256, 0, stream>>>(
        bufB, W3, as3, ad3, flag, hb, as_, ad_);
    gat_gather<false, true><<<gat_grid, 256, 0, stream>>>(
        rowptr, csr_src, as_, ad_, (const unsigned short*)hb, b3, d_out, flag);
}

// Round 12
// 291.165 us; speedup vs baseline: 1.1836x; 1.1212x over previous
//
#include <hip/hip_runtime.h>
#include <hip/hip_bf16.h>
#include <math.h>

#define N_NODES 50000
#define N_EDGES 800000
#define ET_EDGES (N_EDGES + N_NODES)   // with self-loops
#define NEG_SLOPE 0.2f
#define NBUCK ((N_NODES + 255) / 256)  // 196 dst buckets (256 nodes each)
#define CHUNK 4096                      // edges per binning block

typedef __hip_bfloat16 bf16;

__device__ inline float bfbits(unsigned short u) {
    return __uint_as_float(((unsigned)u) << 16);
}
__device__ inline float bflo(unsigned u) { return __uint_as_float(u << 16); }
__device__ inline float bfhi(unsigned u) { return __uint_as_float(u & 0xffff0000u); }

// ---------------- dtype detection ----------------
__global__ void detect_dtype(const unsigned short* __restrict__ w1raw,
                             unsigned* __restrict__ flag)
{
    int t = threadIdx.x;
    float v0 = bfbits(w1raw[2 * t]);
    float v1 = bfbits(w1raw[2 * t + 1]);
    bool bad = !(fabsf(v0) <= 64.f && fabsf(v1) <= 64.f);  // NaN -> bad
    unsigned long long b = __ballot(bad);
    if (t == 0) *flag = (b == 0ull) ? 1u : 0u;
}

// ---------------- param conversion (12 small tensors -> fp32) ----------------
struct CvtArgs {
    const void* src[12];
    float*      dst[12];
    int         n[12];
};

__global__ __launch_bounds__(256)
void convert_params(CvtArgs a, const unsigned* __restrict__ flag)
{
    bool isbf = (*flag != 0u);
    int which = blockIdx.y;
    int n = a.n[which];
    const void* s = a.src[which];
    float* d = a.dst[which];
    for (int i = blockIdx.x * 256 + threadIdx.x; i < n; i += gridDim.x * 256) {
        d[i] = isbf ? bfbits(((const unsigned short*)s)[i])
                    : ((const float*)s)[i];
    }
}

// ---------------- CSR build (bucketed, no per-node global histogram) --------
// Pass A: per-bucket counts (196 counters; LDS hist -> 196 atomics/block).
__global__ __launch_bounds__(256)
void bucket_hist(const int* __restrict__ ei, int* __restrict__ bcnt)
{
    __shared__ int h[NBUCK];
    const int tid = threadIdx.x;
    if (tid < NBUCK) h[tid] = 0;
    __syncthreads();
    const int e0 = blockIdx.x * CHUNK;
    const int n  = min(CHUNK, ET_EDGES - e0);
    for (int k = tid; k < n; k += 256) {
        int e = e0 + k;
        int d = (e < N_EDGES) ? ei[N_EDGES + e] : e - N_EDGES;
        atomicAdd(&h[d >> 8], 1);
    }
    __syncthreads();
    if (tid < NBUCK && h[tid]) atomicAdd(&bcnt[tid], h[tid]);
}

// Pass B: exclusive scan over 196 bucket counts -> bucket bases + cursors.
__global__ __launch_bounds__(256)
void bucket_scan(const int* __restrict__ bcnt,
                 int* __restrict__ bbase, int* __restrict__ cur256)
{
    __shared__ int s[256];
    int t = threadIdx.x;
    int v = (t < NBUCK) ? bcnt[t] : 0;
    s[t] = v;
    __syncthreads();
    for (int off = 1; off < 256; off <<= 1) {
        int u = (t >= off) ? s[t - off] : 0;
        __syncthreads();
        s[t] += u;
        __syncthreads();
    }
    int excl = s[t] - v;
    if (t < NBUCK) { bbase[t] = excl; cur256[t] = excl; }
    if (t == 0) bbase[NBUCK] = ET_EDGES;
}

// Pass C: bin edges by dst bucket into scratch (bucket-sorted, coalesced).
__global__ __launch_bounds__(256)
void binpass(const int* __restrict__ ei, int* __restrict__ cur256,
             unsigned* __restrict__ scratch)
{
    __shared__ int hist[NBUCK];
    __shared__ int lpre[NBUCK + 1];
    __shared__ int lcur[NBUCK];
    __shared__ int gbase[NBUCK];
    __shared__ int scan_a[256];
    __shared__ unsigned entry[CHUNK];

    const int tid = threadIdx.x;
    const int e0  = blockIdx.x * CHUNK;
    const int n   = min(CHUNK, ET_EDGES - e0);

    if (tid < NBUCK) hist[tid] = 0;
    __syncthreads();

    for (int k = tid; k < n; k += 256) {
        int e = e0 + k;
        int d = (e < N_EDGES) ? ei[N_EDGES + e] : e - N_EDGES;
        atomicAdd(&hist[d >> 8], 1);
    }
    __syncthreads();

    int v = (tid < NBUCK) ? hist[tid] : 0;
    scan_a[tid] = v;
    __syncthreads();
    for (int off = 1; off < 256; off <<= 1) {
        int t = (tid >= off) ? scan_a[tid - off] : 0;
        __syncthreads();
        scan_a[tid] += t;
        __syncthreads();
    }
    if (tid < NBUCK) lpre[tid] = scan_a[tid] - v;
    if (tid == NBUCK - 1) lpre[NBUCK] = scan_a[tid];
    if (tid < NBUCK) {
        gbase[tid] = v ? atomicAdd(&cur256[tid], v) : 0;
        lcur[tid] = 0;
    }
    __syncthreads();

    for (int k = tid; k < n; k += 256) {
        int e = e0 + k;
        int s, d;
        if (e < N_EDGES) { s = ei[e]; d = ei[N_EDGES + e]; }
        else             { s = d = e - N_EDGES; }
        int b = d >> 8;
        int p = atomicAdd(&lcur[b], 1);
        entry[lpre[b] + p] = ((unsigned)s << 8) | (unsigned)(d & 255);
    }
    __syncthreads();

    for (int i = tid; i < n; i += 256) {
        int lo = 0, hi = NBUCK;
        while (hi - lo > 1) {
            int mid = (lo + hi) >> 1;
            if (lpre[mid] <= i) lo = mid; else hi = mid;
        }
        scratch[gbase[lo] + (i - lpre[lo])] = entry[i];
    }
}

// Pass D: per-bucket local count -> prefix -> rowptr; then LDS-cursor scatter.
__global__ __launch_bounds__(256)
void fine_scatter(const int* __restrict__ bbase,
                  const unsigned* __restrict__ scratch,
                  int* __restrict__ csr_src,
                  int* __restrict__ rowptr)
{
    __shared__ int cnt[256];
    __shared__ int pre[256];
    const int tid = threadIdx.x;
    const int b   = blockIdx.x;
    const int nb  = b * 256;
    const int nn  = min(256, N_NODES - nb);
    const int gb  = bbase[b];
    const int ge  = bbase[b + 1];

    cnt[tid] = 0;
    __syncthreads();
    for (int i = gb + tid; i < ge; i += 256)
        atomicAdd(&cnt[scratch[i] & 255u], 1);
    __syncthreads();

    int v = cnt[tid];
    pre[tid] = v;
    __syncthreads();
    for (int off = 1; off < 256; off <<= 1) {
        int t = (tid >= off) ? pre[tid - off] : 0;
        __syncthreads();
        pre[tid] += t;
        __syncthreads();
    }
    int excl = pre[tid] - v + gb;
    if (tid < nn) rowptr[nb + tid] = excl;
    if (b == NBUCK - 1 && tid == 0) rowptr[N_NODES] = ET_EDGES;
    cnt[tid] = excl;    // reuse as cursors
    __syncthreads();

    for (int i = gb + tid; i < ge; i += 256) {
        unsigned e = scratch[i];
        int p = atomicAdd(&cnt[e & 255u], 1);
        csr_src[p] = (int)(e >> 8);
    }
}

// ---------------- GEMM + alpha epilogue (32 rows/block, 8 rows/thread) ------
// XMODE: 1 = dtype-dynamic (layer 1 input), 2 = bf16 (internal layer io)
template<int CIN, int XMODE>
__global__ __launch_bounds__(256)
void gemm_alpha(const void* __restrict__ x,
                const float* __restrict__ W,
                const float* __restrict__ a_src,
                const float* __restrict__ a_dst,
                const unsigned* __restrict__ flag,
                bf16* __restrict__ hb,
                float* __restrict__ as_out,
                float* __restrict__ ad_out)
{
    __shared__ float sW[CIN * 64];
    __shared__ float sx[32 * CIN];
    const bool isbf = (XMODE == 2) || (XMODE == 1 && *flag != 0u);
    const int tid = threadIdx.x;
    const int col = tid & 63;
    const int wv  = tid >> 6;
    const int row0 = blockIdx.x * 32;

    for (int i = tid * 4; i < CIN * 64; i += 1024)
        *(float4*)&sW[i] = *(const float4*)&W[i];

    const long xbase = (long)row0 * CIN;
    const int  tile  = 32 * CIN;
    const int  limit = (N_NODES - row0) * CIN;   // multiple of 4
    if (isbf) {
        const unsigned short* xb = (const unsigned short*)x + xbase;
        for (int i = tid * 4; i < tile; i += 1024) {
            float4 v = {0.f, 0.f, 0.f, 0.f};
            if (i < limit) {
                ushort4 u = *(const ushort4*)&xb[i];
                v.x = bfbits(u.x); v.y = bfbits(u.y);
                v.z = bfbits(u.z); v.w = bfbits(u.w);
            }
            *(float4*)&sx[i] = v;
        }
    } else {
        const float* xf = (const float*)x + xbase;
        for (int i = tid * 4; i < tile; i += 1024) {
            float4 v = {0.f, 0.f, 0.f, 0.f};
            if (i < limit) v = *(const float4*)&xf[i];
            *(float4*)&sx[i] = v;
        }
    }
    __syncthreads();

    const int rbase = wv * 8;
    float acc[8];
#pragma unroll
    for (int r = 0; r < 8; ++r) acc[r] = 0.f;

#pragma unroll 2
    for (int kk = 0; kk < CIN; kk += 4) {
        float w0 = sW[(kk + 0) * 64 + col];
        float w1 = sW[(kk + 1) * 64 + col];
        float w2 = sW[(kk + 2) * 64 + col];
        float w3 = sW[(kk + 3) * 64 + col];
#pragma unroll
        for (int r = 0; r < 8; ++r) {
            const float4 xv = *(const float4*)&sx[(rbase + r) * CIN + kk];
            acc[r] = fmaf(xv.x, w0,
                     fmaf(xv.y, w1,
                     fmaf(xv.z, w2,
                     fmaf(xv.w, w3, acc[r]))));
        }
    }

    const float sa = a_src[col];
    const float sd = a_dst[col];
#pragma unroll
    for (int r = 0; r < 8; ++r) {
        int row = row0 + rbase + r;
        float vs = acc[r] * sa;
        float vd = acc[r] * sd;
#pragma unroll
        for (int off = 32; off > 0; off >>= 1) {
            vs += __shfl_xor(vs, off, 64);
            vd += __shfl_xor(vd, off, 64);
        }
        if (row < N_NODES) {
            hb[(long)row * 64 + col] = __float2bfloat16(acc[r]);
            if (col == 0) { as_out[row] = vs; ad_out[row] = vd; }
        }
    }
}

// ---------------- GAT gather: 16-lane group/node, no-max softmax ------------
// OMODE: 0 = bf16 store (internal layer boundary), 1 = dyn final output.
template<bool DO_ELU, int OMODE>
__global__ __launch_bounds__(256)
void gat_gather(const int* __restrict__ rowptr,
                const int* __restrict__ csr_src,
                const float* __restrict__ as_in,
                const float* __restrict__ ad_in,
                const unsigned short* __restrict__ hb_in,
                const float* __restrict__ bias,
                void* __restrict__ out,
                const unsigned* __restrict__ flag)
{
    const int tid  = threadIdx.x;
    const int lane = tid & 63;
    const int l16  = lane & 15;
    const int gb16 = lane & 48;                    // group base within wave
    const int sub  = l16 >> 3;                     // edge slot 0/1
    const int c8   = (l16 & 7) * 8;                // channel group
    const int node = blockIdx.x * 16 + (tid >> 4); // 16 nodes per block
    if (node >= N_NODES) return;

    const int beg = rowptr[node];
    const int deg = rowptr[node + 1] - beg;
    const float adv = ad_in[node];

    // preload up to 32 edges: 2 per lane (src + unnormalized weight)
    int   msrc0 = 0, msrc1 = 0;
    float mw0 = 0.f, mw1 = 0.f;
    if (l16 < deg) {
        msrc0 = csr_src[beg + l16];
        float v = as_in[msrc0] + adv;
        v = (v > 0.f) ? v : NEG_SLOPE * v;
        mw0 = __expf(fminf(v, 60.f));
    }
    if (16 + l16 < deg) {
        msrc1 = csr_src[beg + 16 + l16];
        float v = as_in[msrc1] + adv;
        v = (v > 0.f) ? v : NEG_SLOPE * v;
        mw1 = __expf(fminf(v, 60.f));
    }

    float a0=0.f,a1=0.f,a2=0.f,a3=0.f,a4=0.f,a5=0.f,a6=0.f,a7=0.f,dsum=0.f;
    const int lim = (deg < 32) ? deg : 32;

#pragma unroll
    for (int j0 = 0; j0 < 16; j0 += 4) {
        if (j0 >= lim) break;
        const int jA = j0 + sub;
        const int jB = j0 + 2 + sub;
        float wA = __shfl(mw0,  gb16 + jA, 64);
        int   sA = __shfl(msrc0, gb16 + jA, 64);
        float wB = __shfl(mw0,  gb16 + jB, 64);
        int   sB = __shfl(msrc0, gb16 + jB, 64);
        uint4 pA = {0u,0u,0u,0u}, pB = {0u,0u,0u,0u};
        const bool vA = jA < lim, vB = jB < lim;
        if (vA) pA = *(const uint4*)&hb_in[(long)sA * 64 + c8];
        if (vB) pB = *(const uint4*)&hb_in[(long)sB * 64 + c8];
        if (!vA) wA = 0.f;
        if (!vB) wB = 0.f;
        a0 = fmaf(wA, bflo(pA.x), a0); a1 = fmaf(wA, bfhi(pA.x), a1);
        a2 = fmaf(wA, bflo(pA.y), a2); a3 = fmaf(wA, bfhi(pA.y), a3);
        a4 = fmaf(wA, bflo(pA.z), a4); a5 = fmaf(wA, bfhi(pA.z), a5);
        a6 = fmaf(wA, bflo(pA.w), a6); a7 = fmaf(wA, bfhi(pA.w), a7);
        a0 = fmaf(wB, bflo(pB.x), a0); a1 = fmaf(wB, bfhi(pB.x), a1);
        a2 = fmaf(wB, bflo(pB.y), a2); a3 = fmaf(wB, bfhi(pB.y), a3);
        a4 = fmaf(wB, bflo(pB.z), a4); a5 = fmaf(wB, bfhi(pB.z), a5);
        a6 = fmaf(wB, bflo(pB.w), a6); a7 = fmaf(wB, bfhi(pB.w), a7);
        dsum += wA + wB;
    }
#pragma unroll
    for (int j0 = 16; j0 < 32; j0 += 4) {
        if (j0 >= lim) break;
        const int jA = j0 + sub;
        const int jB = j0 + 2 + sub;
        float wA = __shfl(mw1,  gb16 + jA - 16, 64);
        int   sA = __shfl(msrc1, gb16 + jA - 16, 64);
        float wB = __shfl(mw1,  gb16 + jB - 16, 64);
        int   sB = __shfl(msrc1, gb16 + jB - 16, 64);
        uint4 pA = {0u,0u,0u,0u}, pB = {0u,0u,0u,0u};
        const bool vA = jA < lim, vB = jB < lim;
        if (vA) pA = *(const uint4*)&hb_in[(long)sA * 64 + c8];
        if (vB) pB = *(const uint4*)&hb_in[(long)sB * 64 + c8];
        if (!vA) wA = 0.f;
        if (!vB) wB = 0.f;
        a0 = fmaf(wA, bflo(pA.x), a0); a1 = fmaf(wA, bfhi(pA.x), a1);
        a2 = fmaf(wA, bflo(pA.y), a2); a3 = fmaf(wA, bfhi(pA.y), a3);
        a4 = fmaf(wA, bflo(pA.z), a4); a5 = fmaf(wA, bfhi(pA.z), a5);
        a6 = fmaf(wA, bflo(pA.w), a6); a7 = fmaf(wA, bfhi(pA.w), a7);
        a0 = fmaf(wB, bflo(pB.x), a0); a1 = fmaf(wB, bfhi(pB.x), a1);
        a2 = fmaf(wB, bflo(pB.y), a2); a3 = fmaf(wB, bfhi(pB.y), a3);
        a4 = fmaf(wB, bflo(pB.z), a4); a5 = fmaf(wB, bfhi(pB.z), a5);
        a6 = fmaf(wB, bflo(pB.w), a6); a7 = fmaf(wB, bfhi(pB.w), a7);
        dsum += wA + wB;
    }
    // rare tail: deg > 32
    for (int j0 = 32; j0 < deg; j0 += 2) {
        const int j = j0 + sub;
        if (j < deg) {
            int sj = csr_src[beg + j];
            float v = as_in[sj] + adv;
            v = (v > 0.f) ? v : NEG_SLOPE * v;
            float wj = __expf(fminf(v, 60.f));
            const uint4 p = *(const uint4*)&hb_in[(long)sj * 64 + c8];
            a0 = fmaf(wj, bflo(p.x), a0); a1 = fmaf(wj, bfhi(p.x), a1);
            a2 = fmaf(wj, bflo(p.y), a2); a3 = fmaf(wj, bfhi(p.y), a3);
            a4 = fmaf(wj, bflo(p.z), a4); a5 = fmaf(wj, bfhi(p.z), a5);
            a6 = fmaf(wj, bflo(p.w), a6); a7 = fmaf(wj, bfhi(p.w), a7);
            dsum += wj;
        }
    }

    a0 += __shfl_xor(a0, 8, 64); a1 += __shfl_xor(a1, 8, 64);
    a2 += __shfl_xor(a2, 8, 64); a3 += __shfl_xor(a3, 8, 64);
    a4 += __shfl_xor(a4, 8, 64); a5 += __shfl_xor(a5, 8, 64);
    a6 += __shfl_xor(a6, 8, 64); a7 += __shfl_xor(a7, 8, 64);
    dsum += __shfl_xor(dsum, 8, 64);

    if (sub == 0) {   // lanes l16 0..7 hold channels c8..c8+7
        float inv = 1.f / dsum;
        float r[8] = {a0, a1, a2, a3, a4, a5, a6, a7};
#pragma unroll
        for (int k = 0; k < 8; ++k) {
            r[k] = r[k] * inv + bias[c8 + k];
            if (DO_ELU) r[k] = (r[k] > 0.f) ? r[k] : expm1f(r[k]);
        }
        long o = (long)node * 64 + c8;
        bool bfst = (OMODE == 0) || (*flag != 0u);
        if (bfst) {
            uint4 u;
            u.x = ((unsigned)__bfloat16_as_ushort(__float2bfloat16(r[0]))) |
                  (((unsigned)__bfloat16_as_ushort(__float2bfloat16(r[1]))) << 16);
            u.y = ((unsigned)__bfloat16_as_ushort(__float2bfloat16(r[2]))) |
                  (((unsigned)__bfloat16_as_ushort(__float2bfloat16(r[3]))) << 16);
            u.z = ((unsigned)__bfloat16_as_ushort(__float2bfloat16(r[4]))) |
                  (((unsigned)__bfloat16_as_ushort(__float2bfloat16(r[5]))) << 16);
            u.w = ((unsigned)__bfloat16_as_ushort(__float2bfloat16(r[6]))) |
                  (((unsigned)__bfloat16_as_ushort(__float2bfloat16(r[7]))) << 16);
            *(uint4*)&((unsigned short*)out)[o] = u;
        } else {
            float4 f0 = {r[0], r[1], r[2], r[3]};
            float4 f1 = {r[4], r[5], r[6], r[7]};
            *(float4*)&((float*)out)[o]     = f0;
            *(float4*)&((float*)out)[o + 4] = f1;
        }
    }
}

extern "C" void kernel_launch(void* const* d_in, const int* in_sizes, int n_in,
                              void* d_out, int out_size, void* d_ws, size_t ws_size,
                              hipStream_t stream)
{
    const void* x  = d_in[0];
    const int*  ei = (const int*)d_in[1];
    const void* pW1 = d_in[2],  *pas1 = d_in[3],  *pad1 = d_in[4],  *pb1 = d_in[5];
    const void* pW2 = d_in[6],  *pas2 = d_in[7],  *pad2 = d_in[8],  *pb2 = d_in[9];
    const void* pW3 = d_in[10], *pas3 = d_in[11], *pad3 = d_in[12], *pb3 = d_in[13];

    float* ws = (float*)d_ws;
    float*    bufA   = ws;                          // hbA bf16 lower, scratch upper
    float*    bufB   = bufA + (long)N_NODES * 64;   // hbB bf16 (layer io)
    float*    as_    = bufB + (long)N_NODES * 64;
    float*    ad_    = as_ + N_NODES;
    int*      bcnt   = (int*)(ad_ + N_NODES);       // NBUCK
    int*      bbase  = bcnt + NBUCK;                // NBUCK+1
    int*      cur256 = bbase + NBUCK + 1;           // NBUCK
    int*      rowptr = cur256 + NBUCK;              // N+1
    int*      csr_src= rowptr + N_NODES + 1;        // 3.4 MB
    float*    prm    = (float*)(csr_src + ET_EDGES);
    unsigned* flag   = (unsigned*)(prm + 20000);
    bf16*     hbA    = (bf16*)bufA;
    bf16*     hbB    = (bf16*)bufB;
    unsigned* scratch= (unsigned*)(bufA + (long)N_NODES * 32);  // upper half of bufA

    float* W1 = prm;     float* as1 = W1 + 8192; float* ad1 = as1 + 64; float* b1 = ad1 + 64;
    float* W2 = b1 + 64; float* as2 = W2 + 4096; float* ad2 = as2 + 64; float* b2 = ad2 + 64;
    float* W3 = b2 + 64; float* as3 = W3 + 4096; float* ad3 = as3 + 64; float* b3 = ad3 + 64;

    detect_dtype<<<1, 64, 0, stream>>>((const unsigned short*)pW1, flag);

    CvtArgs ca;
    const void* srcs[12] = {pW1, pas1, pad1, pb1, pW2, pas2, pad2, pb2, pW3, pas3, pad3, pb3};
    float*      dsts[12] = {W1, as1, ad1, b1, W2, as2, ad2, b2, W3, as3, ad3, b3};
    int         ns[12]   = {8192, 64, 64, 64, 4096, 64, 64, 64, 4096, 64, 64, 64};
    for (int i = 0; i < 12; ++i) { ca.src[i] = srcs[i]; ca.dst[i] = dsts[i]; ca.n[i] = ns[i]; }
    convert_params<<<dim3(8, 12), 256, 0, stream>>>(ca, flag);

    // ---- CSR build: bucket hist -> bucket scan -> binpass -> fine scatter ----
    const int chunk_grid = (ET_EDGES + CHUNK - 1) / CHUNK;
    hipMemsetAsync(bcnt, 0, (size_t)NBUCK * 4, stream);
    bucket_hist<<<chunk_grid, 256, 0, stream>>>(ei, bcnt);
    bucket_scan<<<1, 256, 0, stream>>>(bcnt, bbase, cur256);
    binpass<<<chunk_grid, 256, 0, stream>>>(ei, cur256, scratch);
    fine_scatter<<<NBUCK, 256, 0, stream>>>(bbase, scratch, csr_src, rowptr);

    const int gemm_grid = (N_NODES + 31) / 32;
    const int gat_grid  = (N_NODES + 15) / 16;

    // ---------- Layer 1 ----------
    gemm_alpha<128, 1><<<gemm_grid, 256, 0, stream>>>(
        x, W1, as1, ad1, flag, hbA, as_, ad_);
    gat_gather<true, 0><<<gat_grid, 256, 0, stream>>>(
        rowptr, csr_src, as_, ad_, (const unsigned short*)hbA, b1, hbB, flag);

    // ---------- Layer 2 (bf16 layer io) ----------
    gemm_alpha<64, 2><<<gemm_grid, 256, 0, stream>>>(
        hbB, W2, as2, ad2, flag, hbA, as_, ad_);
    gat_gather<true, 0><<<gat_grid, 256, 0, stream>>>(
        rowptr, csr_src, as_, ad_, (const unsigned short*)hbA, b2, hbB, flag);

    // ---------- Layer 3 ----------
    gemm_alpha<64, 2><<<gemm_grid, 256, 0, stream>>>(
        hbB, W3, as3, ad3, flag, hbA, as_, ad_);
    gat_gather<false, 1><<<gat_grid, 256, 0, stream>>>(
        rowptr, csr_src, as_, ad_, (const unsigned short*)hbA, b3, d_out, flag);
}

// Round 13
// 284.158 us; speedup vs baseline: 1.2128x; 1.0247x over previous
//
#include <hip/hip_runtime.h>
#include <hip/hip_bf16.h>
#include <math.h>

#define N_NODES 50000
#define N_EDGES 800000
#define ET_EDGES (N_EDGES + N_NODES)   // with self-loops
#define NEG_SLOPE 0.2f
#define NBUCK ((N_NODES + 255) / 256)  // 196 dst buckets (256 nodes each)
#define CHUNK 4096                      // edges per binning block
#define CAP   8192                      // scratch slots per bucket (>50 sigma)

typedef __hip_bfloat16 bf16;

__device__ inline float bfbits(unsigned short u) {
    return __uint_as_float(((unsigned)u) << 16);
}
__device__ inline float bflo(unsigned u) { return __uint_as_float(u << 16); }
__device__ inline float bfhi(unsigned u) { return __uint_as_float(u & 0xffff0000u); }

// ---------------- dtype detection ----------------
__global__ void detect_dtype(const unsigned short* __restrict__ w1raw,
                             unsigned* __restrict__ flag)
{
    int t = threadIdx.x;
    float v0 = bfbits(w1raw[2 * t]);
    float v1 = bfbits(w1raw[2 * t + 1]);
    bool bad = !(fabsf(v0) <= 64.f && fabsf(v1) <= 64.f);  // NaN -> bad
    unsigned long long b = __ballot(bad);
    if (t == 0) *flag = (b == 0ull) ? 1u : 0u;
}

// ---------------- param conversion (12 small tensors -> fp32) ----------------
struct CvtArgs {
    const void* src[12];
    float*      dst[12];
    int         n[12];
};

__global__ __launch_bounds__(256)
void convert_params(CvtArgs a, const unsigned* __restrict__ flag)
{
    bool isbf = (*flag != 0u);
    int which = blockIdx.y;
    int n = a.n[which];
    const void* s = a.src[which];
    float* d = a.dst[which];
    for (int i = blockIdx.x * 256 + threadIdx.x; i < n; i += gridDim.x * 256) {
        d[i] = isbf ? bfbits(((const unsigned short*)s)[i])
                    : ((const float*)s)[i];
    }
}

// ---------------- CSR build ----------------
// cur256[b] starts at b*CAP; binpass appends into fixed-capacity segments,
// so no pre-histogram pass over the edge list is needed.
__global__ void init_cur(int* __restrict__ cur256)
{
    int t = threadIdx.x;
    if (t < NBUCK) cur256[t] = t * CAP;
}

// Pass C: bin edges by dst bucket into per-bucket scratch segments.
__global__ __launch_bounds__(256)
void binpass(const int* __restrict__ ei, int* __restrict__ cur256,
             unsigned* __restrict__ scratch)
{
    __shared__ int hist[NBUCK];
    __shared__ int lpre[NBUCK + 1];
    __shared__ int lcur[NBUCK];
    __shared__ int gbase[NBUCK];
    __shared__ int scan_a[256];
    __shared__ unsigned entry[CHUNK];

    const int tid = threadIdx.x;
    const int e0  = blockIdx.x * CHUNK;
    const int n   = min(CHUNK, ET_EDGES - e0);

    if (tid < NBUCK) hist[tid] = 0;
    __syncthreads();

    for (int k = tid; k < n; k += 256) {
        int e = e0 + k;
        int d = (e < N_EDGES) ? ei[N_EDGES + e] : e - N_EDGES;
        atomicAdd(&hist[d >> 8], 1);
    }
    __syncthreads();

    int v = (tid < NBUCK) ? hist[tid] : 0;
    scan_a[tid] = v;
    __syncthreads();
    for (int off = 1; off < 256; off <<= 1) {
        int t = (tid >= off) ? scan_a[tid - off] : 0;
        __syncthreads();
        scan_a[tid] += t;
        __syncthreads();
    }
    if (tid < NBUCK) lpre[tid] = scan_a[tid] - v;
    if (tid == NBUCK - 1) lpre[NBUCK] = scan_a[tid];
    if (tid < NBUCK) {
        gbase[tid] = v ? atomicAdd(&cur256[tid], v) : 0;
        lcur[tid] = 0;
    }
    __syncthreads();

    for (int k = tid; k < n; k += 256) {
        int e = e0 + k;
        int s, d;
        if (e < N_EDGES) { s = ei[e]; d = ei[N_EDGES + e]; }
        else             { s = d = e - N_EDGES; }
        int b = d >> 8;
        int p = atomicAdd(&lcur[b], 1);
        entry[lpre[b] + p] = ((unsigned)s << 8) | (unsigned)(d & 255);
    }
    __syncthreads();

    for (int i = tid; i < n; i += 256) {
        int lo = 0, hi = NBUCK;
        while (hi - lo > 1) {
            int mid = (lo + hi) >> 1;
            if (lpre[mid] <= i) lo = mid; else hi = mid;
        }
        scratch[gbase[lo] + (i - lpre[lo])] = entry[i];
    }
}

// Pass B': exclusive scan over realized bucket counts -> true bucket bases.
__global__ __launch_bounds__(256)
void bucket_scan(const int* __restrict__ cur256, int* __restrict__ bbase)
{
    __shared__ int s[256];
    int t = threadIdx.x;
    int v = (t < NBUCK) ? (cur256[t] - t * CAP) : 0;
    s[t] = v;
    __syncthreads();
    for (int off = 1; off < 256; off <<= 1) {
        int u = (t >= off) ? s[t - off] : 0;
        __syncthreads();
        s[t] += u;
        __syncthreads();
    }
    if (t < NBUCK) bbase[t] = s[t] - v;
    if (t == 0) bbase[NBUCK] = ET_EDGES;
}

// Pass D: per-bucket local count -> prefix -> rowptr; then LDS-cursor scatter.
__global__ __launch_bounds__(256)
void fine_scatter(const int* __restrict__ bbase,
                  const unsigned* __restrict__ scratch,
                  int* __restrict__ csr_src,
                  int* __restrict__ rowptr)
{
    __shared__ int cnt[256];
    __shared__ int pre[256];
    const int tid = threadIdx.x;
    const int b   = blockIdx.x;
    const int nb  = b * 256;
    const int nn  = min(256, N_NODES - nb);
    const int gb  = bbase[b];
    const int n   = bbase[b + 1] - gb;
    const long seg = (long)b * CAP;

    cnt[tid] = 0;
    __syncthreads();
    for (int i = tid; i < n; i += 256)
        atomicAdd(&cnt[scratch[seg + i] & 255u], 1);
    __syncthreads();

    int v = cnt[tid];
    pre[tid] = v;
    __syncthreads();
    for (int off = 1; off < 256; off <<= 1) {
        int t = (tid >= off) ? pre[tid - off] : 0;
        __syncthreads();
        pre[tid] += t;
        __syncthreads();
    }
    int excl = pre[tid] - v + gb;
    if (tid < nn) rowptr[nb + tid] = excl;
    if (b == NBUCK - 1 && tid == 0) rowptr[N_NODES] = ET_EDGES;
    cnt[tid] = excl;    // reuse as cursors
    __syncthreads();

    for (int i = tid; i < n; i += 256) {
        unsigned e = scratch[seg + i];
        int p = atomicAdd(&cnt[e & 255u], 1);
        csr_src[p] = (int)(e >> 8);
    }
}

// ---------------- GEMM + alpha epilogue (32 rows/block, 8 rows/thread) ------
// XMODE: 1 = dtype-dynamic (layer 1 input), 2 = bf16 (internal layer io)
template<int CIN, int XMODE>
__global__ __launch_bounds__(256)
void gemm_alpha(const void* __restrict__ x,
                const float* __restrict__ W,
                const float* __restrict__ a_src,
                const float* __restrict__ a_dst,
                const unsigned* __restrict__ flag,
                bf16* __restrict__ hb,
                float* __restrict__ as_out,
                float* __restrict__ ad_out)
{
    __shared__ float sW[CIN * 64];
    __shared__ float sx[32 * CIN];
    const bool isbf = (XMODE == 2) || (XMODE == 1 && *flag != 0u);
    const int tid = threadIdx.x;
    const int col = tid & 63;
    const int wv  = tid >> 6;
    const int row0 = blockIdx.x * 32;

    for (int i = tid * 4; i < CIN * 64; i += 1024)
        *(float4*)&sW[i] = *(const float4*)&W[i];

    const long xbase = (long)row0 * CIN;
    const int  tile  = 32 * CIN;
    const int  limit = (N_NODES - row0) * CIN;   // multiple of 4
    if (isbf) {
        const unsigned short* xb = (const unsigned short*)x + xbase;
        for (int i = tid * 4; i < tile; i += 1024) {
            float4 v = {0.f, 0.f, 0.f, 0.f};
            if (i < limit) {
                ushort4 u = *(const ushort4*)&xb[i];
                v.x = bfbits(u.x); v.y = bfbits(u.y);
                v.z = bfbits(u.z); v.w = bfbits(u.w);
            }
            *(float4*)&sx[i] = v;
        }
    } else {
        const float* xf = (const float*)x + xbase;
        for (int i = tid * 4; i < tile; i += 1024) {
            float4 v = {0.f, 0.f, 0.f, 0.f};
            if (i < limit) v = *(const float4*)&xf[i];
            *(float4*)&sx[i] = v;
        }
    }
    __syncthreads();

    const int rbase = wv * 8;
    float acc[8];
#pragma unroll
    for (int r = 0; r < 8; ++r) acc[r] = 0.f;

#pragma unroll 2
    for (int kk = 0; kk < CIN; kk += 4) {
        float w0 = sW[(kk + 0) * 64 + col];
        float w1 = sW[(kk + 1) * 64 + col];
        float w2 = sW[(kk + 2) * 64 + col];
        float w3 = sW[(kk + 3) * 64 + col];
#pragma unroll
        for (int r = 0; r < 8; ++r) {
            const float4 xv = *(const float4*)&sx[(rbase + r) * CIN + kk];
            acc[r] = fmaf(xv.x, w0,
                     fmaf(xv.y, w1,
                     fmaf(xv.z, w2,
                     fmaf(xv.w, w3, acc[r]))));
        }
    }

    const float sa = a_src[col];
    const float sd = a_dst[col];
#pragma unroll
    for (int r = 0; r < 8; ++r) {
        int row = row0 + rbase + r;
        float vs = acc[r] * sa;
        float vd = acc[r] * sd;
#pragma unroll
        for (int off = 32; off > 0; off >>= 1) {
            vs += __shfl_xor(vs, off, 64);
            vd += __shfl_xor(vd, off, 64);
        }
        if (row < N_NODES) {
            hb[(long)row * 64 + col] = __float2bfloat16(acc[r]);
            if (col == 0) { as_out[row] = vs; ad_out[row] = vd; }
        }
    }
}

// ---------------- GAT gather: 16-lane group/node, no-max softmax ------------
// 32-edge register cache; main loops process 8 edges/iter with 4 uint4 loads
// in flight per lane (MLP). OMODE: 0 = bf16 store, 1 = dyn final output.
#define EDGE4_FMA(wX, pX)                                                    \
    a0 = fmaf(wX, bflo(pX.x), a0); a1 = fmaf(wX, bfhi(pX.x), a1);            \
    a2 = fmaf(wX, bflo(pX.y), a2); a3 = fmaf(wX, bfhi(pX.y), a3);            \
    a4 = fmaf(wX, bflo(pX.z), a4); a5 = fmaf(wX, bfhi(pX.z), a5);            \
    a6 = fmaf(wX, bflo(pX.w), a6); a7 = fmaf(wX, bfhi(pX.w), a7);

template<bool DO_ELU, int OMODE>
__global__ __launch_bounds__(256)
void gat_gather(const int* __restrict__ rowptr,
                const int* __restrict__ csr_src,
                const float* __restrict__ as_in,
                const float* __restrict__ ad_in,
                const unsigned short* __restrict__ hb_in,
                const float* __restrict__ bias,
                void* __restrict__ out,
                const unsigned* __restrict__ flag)
{
    const int tid  = threadIdx.x;
    const int lane = tid & 63;
    const int l16  = lane & 15;
    const int gb16 = lane & 48;                    // group base within wave
    const int sub  = l16 >> 3;                     // edge slot 0/1
    const int c8   = (l16 & 7) * 8;                // channel group
    const int node = blockIdx.x * 16 + (tid >> 4); // 16 nodes per block
    if (node >= N_NODES) return;

    const int beg = rowptr[node];
    const int deg = rowptr[node + 1] - beg;
    const float adv = ad_in[node];

    // preload up to 32 edges: 2 per lane (src + unnormalized weight)
    int   msrc0 = 0, msrc1 = 0;
    float mw0 = 0.f, mw1 = 0.f;
    if (l16 < deg) {
        msrc0 = csr_src[beg + l16];
        float v = as_in[msrc0] + adv;
        v = (v > 0.f) ? v : NEG_SLOPE * v;
        mw0 = __expf(fminf(v, 60.f));
    }
    if (16 + l16 < deg) {
        msrc1 = csr_src[beg + 16 + l16];
        float v = as_in[msrc1] + adv;
        v = (v > 0.f) ? v : NEG_SLOPE * v;
        mw1 = __expf(fminf(v, 60.f));
    }

    float a0=0.f,a1=0.f,a2=0.f,a3=0.f,a4=0.f,a5=0.f,a6=0.f,a7=0.f,dsum=0.f;
    const int lim = (deg < 32) ? deg : 32;

    // bank 0: edges 0..15, 8 per iteration (4 loads in flight per lane)
#pragma unroll
    for (int j0 = 0; j0 < 16; j0 += 8) {
        if (j0 >= lim) break;
        const int jA = j0 + sub,     jB = j0 + 2 + sub;
        const int jC = j0 + 4 + sub, jD = j0 + 6 + sub;
        float wA = __shfl(mw0,   gb16 + jA, 64);
        int   sA = __shfl(msrc0, gb16 + jA, 64);
        float wB = __shfl(mw0,   gb16 + jB, 64);
        int   sB = __shfl(msrc0, gb16 + jB, 64);
        float wC = __shfl(mw0,   gb16 + jC, 64);
        int   sC = __shfl(msrc0, gb16 + jC, 64);
        float wD = __shfl(mw0,   gb16 + jD, 64);
        int   sD = __shfl(msrc0, gb16 + jD, 64);
        uint4 pA={0u,0u,0u,0u}, pB={0u,0u,0u,0u}, pC={0u,0u,0u,0u}, pD={0u,0u,0u,0u};
        const bool vA = jA < lim, vB = jB < lim, vC = jC < lim, vD = jD < lim;
        if (vA) pA = *(const uint4*)&hb_in[(long)sA * 64 + c8];
        if (vB) pB = *(const uint4*)&hb_in[(long)sB * 64 + c8];
        if (vC) pC = *(const uint4*)&hb_in[(long)sC * 64 + c8];
        if (vD) pD = *(const uint4*)&hb_in[(long)sD * 64 + c8];
        if (!vA) wA = 0.f;
        if (!vB) wB = 0.f;
        if (!vC) wC = 0.f;
        if (!vD) wD = 0.f;
        EDGE4_FMA(wA, pA) EDGE4_FMA(wB, pB) EDGE4_FMA(wC, pC) EDGE4_FMA(wD, pD)
        dsum += (wA + wB) + (wC + wD);
    }
    // bank 1: edges 16..31
#pragma unroll
    for (int j0 = 16; j0 < 32; j0 += 8) {
        if (j0 >= lim) break;
        const int jA = j0 + sub,     jB = j0 + 2 + sub;
        const int jC = j0 + 4 + sub, jD = j0 + 6 + sub;
        float wA = __shfl(mw1,   gb16 + jA - 16, 64);
        int   sA = __shfl(msrc1, gb16 + jA - 16, 64);
        float wB = __shfl(mw1,   gb16 + jB - 16, 64);
        int   sB = __shfl(msrc1, gb16 + jB - 16, 64);
        float wC = __shfl(mw1,   gb16 + jC - 16, 64);
        int   sC = __shfl(msrc1, gb16 + jC - 16, 64);
        float wD = __shfl(mw1,   gb16 + jD - 16, 64);
        int   sD = __shfl(msrc1, gb16 + jD - 16, 64);
        uint4 pA={0u,0u,0u,0u}, pB={0u,0u,0u,0u}, pC={0u,0u,0u,0u}, pD={0u,0u,0u,0u};
        const bool vA = jA < lim, vB = jB < lim, vC = jC < lim, vD = jD < lim;
        if (vA) pA = *(const uint4*)&hb_in[(long)sA * 64 + c8];
        if (vB) pB = *(const uint4*)&hb_in[(long)sB * 64 + c8];
        if (vC) pC = *(const uint4*)&hb_in[(long)sC * 64 + c8];
        if (vD) pD = *(const uint4*)&hb_in[(long)sD * 64 + c8];
        if (!vA) wA = 0.f;
        if (!vB) wB = 0.f;
        if (!vC) wC = 0.f;
        if (!vD) wD = 0.f;
        EDGE4_FMA(wA, pA) EDGE4_FMA(wB, pB) EDGE4_FMA(wC, pC) EDGE4_FMA(wD, pD)
        dsum += (wA + wB) + (wC + wD);
    }
    // rare tail: deg > 32
    for (int j0 = 32; j0 < deg; j0 += 2) {
        const int j = j0 + sub;
        if (j < deg) {
            int sj = csr_src[beg + j];
            float v = as_in[sj] + adv;
            v = (v > 0.f) ? v : NEG_SLOPE * v;
            float wj = __expf(fminf(v, 60.f));
            const uint4 p = *(const uint4*)&hb_in[(long)sj * 64 + c8];
            EDGE4_FMA(wj, p)
            dsum += wj;
        }
    }

    a0 += __shfl_xor(a0, 8, 64); a1 += __shfl_xor(a1, 8, 64);
    a2 += __shfl_xor(a2, 8, 64); a3 += __shfl_xor(a3, 8, 64);
    a4 += __shfl_xor(a4, 8, 64); a5 += __shfl_xor(a5, 8, 64);
    a6 += __shfl_xor(a6, 8, 64); a7 += __shfl_xor(a7, 8, 64);
    dsum += __shfl_xor(dsum, 8, 64);

    if (sub == 0) {   // lanes l16 0..7 hold channels c8..c8+7
        float inv = 1.f / dsum;
        float r[8] = {a0, a1, a2, a3, a4, a5, a6, a7};
#pragma unroll
        for (int k = 0; k < 8; ++k) {
            r[k] = r[k] * inv + bias[c8 + k];
            if (DO_ELU) r[k] = (r[k] > 0.f) ? r[k] : expm1f(r[k]);
        }
        long o = (long)node * 64 + c8;
        bool bfst = (OMODE == 0) || (*flag != 0u);
        if (bfst) {
            uint4 u;
            u.x = ((unsigned)__bfloat16_as_ushort(__float2bfloat16(r[0]))) |
                  (((unsigned)__bfloat16_as_ushort(__float2bfloat16(r[1]))) << 16);
            u.y = ((unsigned)__bfloat16_as_ushort(__float2bfloat16(r[2]))) |
                  (((unsigned)__bfloat16_as_ushort(__float2bfloat16(r[3]))) << 16);
            u.z = ((unsigned)__bfloat16_as_ushort(__float2bfloat16(r[4]))) |
                  (((unsigned)__bfloat16_as_ushort(__float2bfloat16(r[5]))) << 16);
            u.w = ((unsigned)__bfloat16_as_ushort(__float2bfloat16(r[6]))) |
                  (((unsigned)__bfloat16_as_ushort(__float2bfloat16(r[7]))) << 16);
            *(uint4*)&((unsigned short*)out)[o] = u;
        } else {
            float4 f0 = {r[0], r[1], r[2], r[3]};
            float4 f1 = {r[4], r[5], r[6], r[7]};
            *(float4*)&((float*)out)[o]     = f0;
            *(float4*)&((float*)out)[o + 4] = f1;
        }
    }
}

extern "C" void kernel_launch(void* const* d_in, const int* in_sizes, int n_in,
                              void* d_out, int out_size, void* d_ws, size_t ws_size,
                              hipStream_t stream)
{
    const void* x  = d_in[0];
    const int*  ei = (const int*)d_in[1];
    const void* pW1 = d_in[2],  *pas1 = d_in[3],  *pad1 = d_in[4],  *pb1 = d_in[5];
    const void* pW2 = d_in[6],  *pas2 = d_in[7],  *pad2 = d_in[8],  *pb2 = d_in[9];
    const void* pW3 = d_in[10], *pas3 = d_in[11], *pad3 = d_in[12], *pb3 = d_in[13];

    float* ws = (float*)d_ws;
    bf16*     hbA    = (bf16*)ws;                              // 6.4 MB
    bf16*     hbB    = (bf16*)(ws + (long)N_NODES * 32);       // 6.4 MB
    float*    as_    = ws + (long)N_NODES * 64;
    float*    ad_    = as_ + N_NODES;
    int*      bbase  = (int*)(ad_ + N_NODES);                  // NBUCK+1
    int*      cur256 = bbase + NBUCK + 1;                      // NBUCK
    int*      rowptr = cur256 + NBUCK;                         // N+1
    int*      csr_src= rowptr + N_NODES + 1;                   // 3.4 MB
    unsigned* scratch= (unsigned*)(csr_src + ET_EDGES);        // NBUCK*CAP 6.4 MB
    float*    prm    = (float*)(scratch + (long)NBUCK * CAP);
    unsigned* flag   = (unsigned*)(prm + 20000);

    float* W1 = prm;     float* as1 = W1 + 8192; float* ad1 = as1 + 64; float* b1 = ad1 + 64;
    float* W2 = b1 + 64; float* as2 = W2 + 4096; float* ad2 = as2 + 64; float* b2 = ad2 + 64;
    float* W3 = b2 + 64; float* as3 = W3 + 4096; float* ad3 = as3 + 64; float* b3 = ad3 + 64;

    detect_dtype<<<1, 64, 0, stream>>>((const unsigned short*)pW1, flag);

    CvtArgs ca;
    const void* srcs[12] = {pW1, pas1, pad1, pb1, pW2, pas2, pad2, pb2, pW3, pas3, pad3, pb3};
    float*      dsts[12] = {W1, as1, ad1, b1, W2, as2, ad2, b2, W3, as3, ad3, b3};
    int         ns[12]   = {8192, 64, 64, 64, 4096, 64, 64, 64, 4096, 64, 64, 64};
    for (int i = 0; i < 12; ++i) { ca.src[i] = srcs[i]; ca.dst[i] = dsts[i]; ca.n[i] = ns[i]; }
    convert_params<<<dim3(8, 12), 256, 0, stream>>>(ca, flag);

    // ---- CSR build: segment-append binpass -> scan -> fine scatter ----
    const int chunk_grid = (ET_EDGES + CHUNK - 1) / CHUNK;
    init_cur<<<1, 256, 0, stream>>>(cur256);
    binpass<<<chunk_grid, 256, 0, stream>>>(ei, cur256, scratch);
    bucket_scan<<<1, 256, 0, stream>>>(cur256, bbase);
    fine_scatter<<<NBUCK, 256, 0, stream>>>(bbase, scratch, csr_src, rowptr);

    const int gemm_grid = (N_NODES + 31) / 32;
    const int gat_grid  = (N_NODES + 15) / 16;

    // ---------- Layer 1 ----------
    gemm_alpha<128, 1><<<gemm_grid, 256, 0, stream>>>(
        x, W1, as1, ad1, flag, hbA, as_, ad_);
    gat_gather<true, 0><<<gat_grid, 256, 0, stream>>>(
        rowptr, csr_src, as_, ad_, (const unsigned short*)hbA, b1, hbB, flag);

    // ---------- Layer 2 (bf16 layer io) ----------
    gemm_alpha<64, 2><<<gemm_grid, 256, 0, stream>>>(
        hbB, W2, as2, ad2, flag, hbA, as_, ad_);
    gat_gather<true, 0><<<gat_grid, 256, 0, stream>>>(
        rowptr, csr_src, as_, ad_, (const unsigned short*)hbA, b2, hbB, flag);

    // ---------- Layer 3 ----------
    gemm_alpha<64, 2><<<gemm_grid, 256, 0, stream>>>(
        hbB, W3, as3, ad3, flag, hbA, as_, ad_);
    gat_gather<false, 1><<<gat_grid, 256, 0, stream>>>(
        rowptr, csr_src, as_, ad_, (const unsigned short*)hbA, b3, d_out, flag);
}